// Round 16
// baseline (370.714 us; speedup 1.0000x reference)
//
#include <hip/hip_runtime.h>
#include <hip/hip_bf16.h>

#define NB 4096
#define PLEN 14
#define NROWS (NB*PLEN)     // 57344 per input
#define BN_EPS 1e-5f

typedef __bf16 bf16x8 __attribute__((ext_vector_type(8)));
typedef float  f32x4  __attribute__((ext_vector_type(4)));

// ---------------- wprep: zero stats + all weight converts in one launch ----
__global__ __launch_bounds__(256) void wprep_kernel(
    const float* __restrict__ W2, const float* __restrict__ W3,
    const float* __restrict__ W4, const float* __restrict__ W5,
    __bf16* __restrict__ wt2, __bf16* __restrict__ wt3,
    __bf16* __restrict__ wt4, __bf16* __restrict__ wt5b,
    float* __restrict__ stats)
{
    int idx = blockIdx.x*256 + threadIdx.x;
    if (idx < 20480) { stats[idx] = 0.f; return; }
    idx -= 20480;
    if (idx < 4096) { int n = idx>>6, k = idx&63; wt2[idx] = (__bf16)W2[k*64+n]; return; }
    idx -= 4096;
    if (idx < 4096) { int n = idx>>6, k = idx&63; wt3[idx] = (__bf16)W3[k*64+n]; return; }
    idx -= 4096;
    if (idx < 8192) { int n = idx>>6, k = idx&63; wt4[idx] = (__bf16)W4[k*128+n]; return; }
    idx -= 8192;
    // W5 blocked: [16 c][16 kg][64 n][8 kk]
    int kk = idx & 7, n = (idx >> 3) & 63, kg = (idx >> 9) & 15, c = idx >> 13;
    wt5b[idx] = (__bf16)W5[(kg*8 + kk)*1024 + c*64 + n];
}

// ---------------- Layer 1 (both inputs): agg(x) @ W1 + b1, stats ----------
__global__ __launch_bounds__(256) void l1_kernel(
    const float* __restrict__ x1,    // [NB][3][PLEN]
    const float* __restrict__ x2,
    const float* __restrict__ W,     // [3][64]
    const float* __restrict__ bias,  // [64]
    __bf16* __restrict__ pre,        // [2*NROWS][64] bf16
    float* __restrict__ stats)       // base; input i at +i*10240
{
    const int col  = threadIdx.x & 63;
    const int sub  = threadIdx.x >> 6;
    const int chain = blockIdx.x * 4 + sub;      // 0..8191 global
    const int inp  = chain >> 12;                // uniform per block
    const float w0 = W[0*64+col], w1 = W[1*64+col], w2 = W[2*64+col];
    const float bb = bias[col];
    const float* xb = (inp ? x2 : x1) + (chain & 4095)*3*PLEN;
    float s = 0.f, s2 = 0.f;
    for (int p = 0; p < PLEN; p++) {
        float u0 = 0.f, u1 = 0.f, u2 = 0.f;
        if (p > 0)      { u0 += xb[p-1]; u1 += xb[PLEN+p-1]; u2 += xb[2*PLEN+p-1]; }
        if (p < PLEN-1) { u0 += xb[p+1]; u1 += xb[PLEN+p+1]; u2 += xb[2*PLEN+p+1]; }
        float v = u0*w0 + u1*w1 + u2*w2 + bb;
        pre[(size_t)(chain*PLEN + p)*64 + col] = (__bf16)v;
        s += v; s2 += v*v;
    }
    __shared__ float ss[4][64], ssq[4][64];
    ss[sub][col] = s; ssq[sub][col] = s2;
    __syncthreads();
    if (sub == 0) {
        float ts  = ss[0][col]+ss[1][col]+ss[2][col]+ss[3][col];
        float ts2 = ssq[0][col]+ssq[1][col]+ssq[2][col]+ssq[3][col];
        atomicAdd(&stats[inp*10240 + col], ts);
        atomicAdd(&stats[inp*10240 + 1024 + col], ts2);
    }
}

// ---------------- fused layer (2-4), both inputs: BN+ReLU+agg -> GEMM -----
// bf16 intermediates (prev/outp); B streamed direct to registers; no sB LDS.
// Plain launch bounds (round-7 lesson: min-waves arg >2 slashes VGPR, spills).
template<int NOUT>
__global__ __launch_bounds__(256) void layer_kernel(
    const __bf16* __restrict__ prev,     // [2*NROWS][64] bf16
    const float* __restrict__ stats_in,  // input-0 slot; +10240 for input 1
    const float* __restrict__ gamma, const float* __restrict__ beta,
    const __bf16* __restrict__ wt,       // [NOUT][64]
    const float* __restrict__ bias,      // [NOUT]
    __bf16* __restrict__ outp,           // [2*NROWS][NOUT] bf16
    float* __restrict__ stats_out)       // input-0 slot; +10240 for input 1
{
    constexpr int KP = 72;
    constexpr int NCH = NOUT/64;
    __shared__ __align__(16) short sA[112*KP];
    const int tid = threadIdx.x, wave = tid >> 6, lane = tid & 63;
    const int m = lane & 15, q = lane >> 4;
    const int rowbase = blockIdx.x * 112;            // global over 114688 rows
    const int soff = (blockIdx.x >> 9) * 10240;      // input select (512 blocks/input)
    const float* sin_ = stats_in + soff;

    // B -> registers (L2-hot, 8/16 KB total)
    bf16x8 breg[NCH][2];
    #pragma unroll
    for (int cc = 0; cc < NCH; ++cc)
        #pragma unroll
        for (int ksi = 0; ksi < 2; ++ksi)
            breg[cc][ksi] = *reinterpret_cast<const bf16x8*>(
                wt + (cc*64 + wave*16 + m)*64 + ksi*32 + q*8);

    // build A = chain_agg(relu(bn(prev))): thread owns 1 chain x 2 cols
    {
        const int ch = tid >> 5, c2 = (tid & 31)*2;
        float mu0 = sin_[c2]*(1.f/NROWS);
        float v0  = sin_[1024+c2]*(1.f/NROWS) - mu0*mu0;
        float a0  = gamma[c2]*rsqrtf(v0+BN_EPS), c0 = beta[c2]-mu0*a0;
        float mu1 = sin_[c2+1]*(1.f/NROWS);
        float v1  = sin_[1024+c2+1]*(1.f/NROWS) - mu1*mu1;
        float a1  = gamma[c2+1]*rsqrtf(v1+BN_EPS), c1 = beta[c2+1]-mu1*a1;
        float h0[14], h1[14];
        const __bf16* src = prev + (size_t)(rowbase + ch*14)*64 + c2;
        #pragma unroll
        for (int r = 0; r < 14; ++r) {
            union { unsigned u; __bf16 b[2]; } ld;
            ld.u = *reinterpret_cast<const unsigned*>(src + r*64);
            h0[r] = fmaxf(a0*(float)ld.b[0] + c0, 0.f);
            h1[r] = fmaxf(a1*(float)ld.b[1] + c1, 0.f);
        }
        #pragma unroll
        for (int r = 0; r < 14; ++r) {
            float g0 = (r>0 ? h0[r-1] : 0.f) + (r<13 ? h0[r+1] : 0.f);
            float g1 = (r>0 ? h1[r-1] : 0.f) + (r<13 ? h1[r+1] : 0.f);
            union { __bf16 b[2]; unsigned u; } pk;
            pk.b[0] = (__bf16)g0; pk.b[1] = (__bf16)g1;
            *reinterpret_cast<unsigned*>(&sA[(ch*14+r)*KP + c2]) = pk.u;
        }
    }
    __syncthreads();

    f32x4 acc[NCH][7];
    #pragma unroll
    for (int cc = 0; cc < NCH; ++cc)
        #pragma unroll
        for (int t = 0; t < 7; ++t) acc[cc][t] = (f32x4){0.f,0.f,0.f,0.f};

    #pragma unroll
    for (int ksi = 0; ksi < 2; ++ksi) {
        bf16x8 af[7];
        #pragma unroll
        for (int t = 0; t < 7; ++t)
            af[t] = *reinterpret_cast<const bf16x8*>(&sA[(t*16+m)*KP + ksi*32 + q*8]);
        #pragma unroll
        for (int cc = 0; cc < NCH; ++cc)
            #pragma unroll
            for (int t = 0; t < 7; ++t)
                acc[cc][t] = __builtin_amdgcn_mfma_f32_16x16x32_bf16(af[t], breg[cc][ksi], acc[cc][t], 0, 0, 0);
    }

    #pragma unroll
    for (int cc = 0; cc < NCH; ++cc) {
        const int ocol = cc*64 + wave*16 + m;
        const float bb = bias[ocol];
        float s = 0.f, s2 = 0.f;
        #pragma unroll
        for (int t = 0; t < 7; ++t)
            #pragma unroll
            for (int r = 0; r < 4; ++r) {
                float v = acc[cc][t][r] + bb;
                outp[(size_t)(rowbase + t*16 + q*4 + r)*NOUT + ocol] = (__bf16)v;
                s += v; s2 += v*v;
            }
        s  += __shfl_xor(s, 16);  s  += __shfl_xor(s, 32);
        s2 += __shfl_xor(s2, 16); s2 += __shfl_xor(s2, 32);
        if (lane < 16) {
            atomicAdd(&stats_out[soff + ocol], s);
            atomicAdd(&stats_out[soff + 1024 + ocol], s2);
        }
    }
}

// ---------------- Layer 5 (both inputs), 256 threads / 4 waves -------------
// Barrier-free main loop, B streamed through registers, bf16 in/out
// (round-11 body). STATS ATOMICS REMOVED: each block stores its per-column
// partial sums non-atomically to part[block][2048]; sreduce_kernel sums the
// 512 blocks per input afterward. l5 previously issued 2.1M f32 atomicAdds
// onto 4096 addresses (512 collisions each) — the suspected ~75us floor.
__global__ __launch_bounds__(256, 1) void l5_kernel(
    const __bf16* __restrict__ prev,     // [2*NROWS][128] bf16 (pre4)
    const float* __restrict__ stats_in,  // input-0 slot
    const float* __restrict__ gamma, const float* __restrict__ beta,
    const __bf16* __restrict__ wtb,      // blocked W5: [16 c][16 kg][64 n][8 kk]
    const float* __restrict__ bias,      // [1024]
    const float* __restrict__ g5,        // gamma5 [1024] (sign select)
    __bf16* __restrict__ osel,           // [2*NB][1024] bf16
    float* __restrict__ part)            // [1024 blocks][2048] partial stats
{
    __shared__ __align__(16) short sA[112*136];   // 30464 B, permuted A rows
    const int tid = threadIdx.x, wave = tid >> 6, lane = tid & 63;
    const int m = lane & 15, q = lane >> 4;
    const int rowbase = blockIdx.x * 112;
    const int soff = (blockIdx.x >> 9) * 10240;
    const float* sin_ = stats_in + soff;
    float* pb = part + (size_t)blockIdx.x * 2048;

    // per-lane B offset within a 16KB chunk, in BYTES: kg = k4*4+q (stride
    // 1024 B), n = wave*16+m (stride 16 B); k4 stride = 4 kg = 4096 B.
    const char* gw = (const char*)wtb;
    const int boffB = q*1024 + (wave*16 + m)*16;

    // prefetch B chunk 0 into registers (covered by A staging below)
    bf16x8 bA[4], bB[4];
    #pragma unroll
    for (int k4 = 0; k4 < 4; ++k4)
        bA[k4] = *reinterpret_cast<const bf16x8*>(gw + boffB + k4*4096);

    // build A = chain_agg(relu(bn(pre4))), PERMUTED rows: thread owns 1 chain x 4 cols
    {
        const int ch = tid >> 5, c4 = (tid & 31)*4;
        float aa[4], cc4[4];
        #pragma unroll
        for (int j = 0; j < 4; ++j) {
            float mu = sin_[c4+j]*(1.f/NROWS);
            float vr = sin_[1024+c4+j]*(1.f/NROWS) - mu*mu;
            aa[j] = gamma[c4+j]*rsqrtf(vr+BN_EPS);
            cc4[j] = beta[c4+j] - mu*aa[j];
        }
        float h[14][4];
        const __bf16* src = prev + (size_t)(rowbase + ch*14)*128 + c4;
        #pragma unroll
        for (int r = 0; r < 14; ++r) {
            union { uint2 u; __bf16 b[4]; } ld;
            ld.u = *reinterpret_cast<const uint2*>(src + r*128);
            h[r][0] = fmaxf(aa[0]*(float)ld.b[0] + cc4[0], 0.f);
            h[r][1] = fmaxf(aa[1]*(float)ld.b[1] + cc4[1], 0.f);
            h[r][2] = fmaxf(aa[2]*(float)ld.b[2] + cc4[2], 0.f);
            h[r][3] = fmaxf(aa[3]*(float)ld.b[3] + cc4[3], 0.f);
        }
        const int qq = ch >> 1, jb = (ch & 1) * 14;
        #pragma unroll
        for (int p = 0; p < 14; ++p) {
            int j = jb + p;
            int slot = (j>>2)*16 + qq*4 + (j&3);
            union { __bf16 b[4]; uint2 u; } pk;
            #pragma unroll
            for (int jj = 0; jj < 4; ++jj) {
                float g = (p>0 ? h[p-1][jj] : 0.f) + (p<13 ? h[p+1][jj] : 0.f);
                pk.b[jj] = (__bf16)g;
            }
            *reinterpret_cast<uint2*>(&sA[slot*136 + c4]) = pk.u;
        }
    }
    __syncthreads();   // the ONLY barrier: sA complete

    // A fragments -> registers (sA never touched again)
    bf16x8 af[7][4];
    #pragma unroll
    for (int t = 0; t < 7; ++t)
        #pragma unroll
        for (int kk = 0; kk < 4; ++kk)
            af[t][kk] = *reinterpret_cast<const bf16x8*>(&sA[(t*16 + m)*136 + kk*32 + q*8]);

    // one c-step: MFMA from bR, epilogue (register chain-max + partial store)
    auto step = [&](int c, bf16x8 (&bR)[4]) {
        f32x4 acc[7];
        #pragma unroll
        for (int t = 0; t < 7; ++t) acc[t] = (f32x4){0.f,0.f,0.f,0.f};
        #pragma unroll
        for (int k4 = 0; k4 < 4; ++k4)
            #pragma unroll
            for (int t = 0; t < 7; ++t)
                acc[t] = __builtin_amdgcn_mfma_f32_16x16x32_bf16(af[t][k4], bR[k4], acc[t], 0, 0, 0);
        const int ocol = c*64 + wave*16 + m;
        const float bb = bias[ocol];
        const float sg = (g5[ocol] >= 0.f) ? 1.f : -1.f;
        float s = 0.f, s2 = 0.f;
        float mx0 = -3.4e38f, mx1 = -3.4e38f;
        #pragma unroll
        for (int t = 0; t < 7; ++t)
            #pragma unroll
            for (int r = 0; r < 4; ++r) {
                float v = acc[t][r] + bb;
                s += v; s2 += v*v;
                float va = sg * v;
                if (t*4 + r < 14) mx0 = fmaxf(mx0, va);
                else              mx1 = fmaxf(mx1, va);
            }
        osel[(size_t)(blockIdx.x*8 + 2*q    )*1024 + ocol] = (__bf16)(sg * mx0);
        osel[(size_t)(blockIdx.x*8 + 2*q + 1)*1024 + ocol] = (__bf16)(sg * mx1);
        s  += __shfl_xor(s, 16);  s  += __shfl_xor(s, 32);
        s2 += __shfl_xor(s2, 16); s2 += __shfl_xor(s2, 32);
        if (lane < 16) {
            pb[ocol]        = s;    // plain stores — summed by sreduce_kernel
            pb[1024 + ocol] = s2;
        }
    };

    #pragma unroll 1
    for (int cc = 0; cc < 16; cc += 2) {
        // even step: prefetch chunk cc+1 -> bB, compute cc from bA
        {
            const char* gb = gw + (size_t)(cc+1)*16384 + boffB;   // BYTES
            #pragma unroll
            for (int k4 = 0; k4 < 4; ++k4)
                bB[k4] = *reinterpret_cast<const bf16x8*>(gb + k4*4096);
        }
        step(cc, bA);
        // odd step: prefetch chunk cc+2 -> bA, compute cc+1 from bB
        if (cc + 2 < 16) {
            const char* gb = gw + (size_t)(cc+2)*16384 + boffB;   // BYTES
            #pragma unroll
            for (int k4 = 0; k4 < 4; ++k4)
                bA[k4] = *reinterpret_cast<const bf16x8*>(gb + k4*4096);
        }
        step(cc + 1, bB);
    }
}

// ---------------- sreduce: sum l5 partials -> stats5 ----------------------
// part layout: [2 inputs x 512 blocks][2048]; output stats[inp*10240+8192+col].
// 16 blocks x 256 threads; thread owns one (inp,col); loop over 512 blocks
// with coalesced 1KB reads per iteration.
__global__ __launch_bounds__(256) void sreduce_kernel(
    const float* __restrict__ part, float* __restrict__ stats)
{
    const int cg  = blockIdx.x*256 + threadIdx.x;   // 0..4095
    const int inp = cg >> 11;
    const int col = cg & 2047;
    const float* p = part + (size_t)inp*512*2048 + col;
    float s = 0.f;
    #pragma unroll 4
    for (int b = 0; b < 512; ++b)
        s += p[(size_t)b*2048];
    stats[inp*10240 + 8192 + col] = s;
}

// ---------------- head+cluster fused, both inputs: one block per batch row -
__global__ __launch_bounds__(256) void headclu_kernel(
    const __bf16* __restrict__ osel,  // [2*NB][1024] bf16
    const float* __restrict__ stats,  // base
    const float* __restrict__ gamma, const float* __restrict__ beta,
    const float* __restrict__ embW, const float* __restrict__ embB,
    const float* __restrict__ cluW,
    float* __restrict__ e1, float* __restrict__ e2,
    float* __restrict__ c1, float* __restrict__ c2,
    float* __restrict__ d1, float* __restrict__ simOut)
{
    const int b = blockIdx.x, tid = threadIdx.x;
    const int wave = tid >> 6, lane = tid & 63;
    __shared__ float red[4][10];
    __shared__ float se[2][10];
    __shared__ float sred[4];

    for (int inp = 0; inp < 2; ++inp) {
        const float* st  = stats + inp*10240 + 8192;
        const __bf16* row = osel + (size_t)(inp*NB + b)*1024;
        float acc[10];
        #pragma unroll
        for (int j = 0; j < 10; ++j) acc[j] = 0.f;
        #pragma unroll
        for (int i = 0; i < 4; ++i) {
            int k = tid + i*256;
            float mu  = st[k]*(1.f/NROWS);
            float var = st[1024+k]*(1.f/NROWS) - mu*mu;
            float a = gamma[k]*rsqrtf(var+BN_EPS);
            float c = beta[k] - mu*a;
            float h = fmaxf(a*(float)row[k] + c, 0.f);
            #pragma unroll
            for (int j = 0; j < 10; ++j) acc[j] += h * embW[k*10 + j];
        }
        #pragma unroll
        for (int j = 0; j < 10; ++j) {
            acc[j] += __shfl_down(acc[j], 32);
            acc[j] += __shfl_down(acc[j], 16);
            acc[j] += __shfl_down(acc[j], 8);
            acc[j] += __shfl_down(acc[j], 4);
            acc[j] += __shfl_down(acc[j], 2);
            acc[j] += __shfl_down(acc[j], 1);
        }
        if (lane == 0)
            #pragma unroll
            for (int j = 0; j < 10; ++j) red[wave][j] = acc[j];
        __syncthreads();
        if (tid < 10) {
            float t = red[0][tid]+red[1][tid]+red[2][tid]+red[3][tid] + embB[tid];
            se[inp][tid] = t;
            (inp ? e2 : e1)[b*10 + tid] = t;
        }
        __syncthreads();

        float ev[10];
        #pragma unroll
        for (int j = 0; j < 10; ++j) ev[j] = se[inp][j];
        float dloc[4], qloc[4], qs = 0.f;
        #pragma unroll
        for (int i = 0; i < 4; ++i) {
            int mm = tid + i*256;
            float dd = 0.f;
            if (mm < 800) {
                #pragma unroll
                for (int j = 0; j < 10; ++j) { float t = ev[j] - cluW[mm*10 + j]; dd += t*t; }
            }
            dloc[i] = dd;
            float qv = (mm < 800) ? 1.f/(1.f + dd) : 0.f;
            qloc[i] = qv; qs += qv;
        }
        float t = qs;
        t += __shfl_down(t,32); t += __shfl_down(t,16); t += __shfl_down(t,8);
        t += __shfl_down(t,4);  t += __shfl_down(t,2);  t += __shfl_down(t,1);
        if (lane == 0) sred[wave] = t;
        __syncthreads();
        float inv = 1.f / (sred[0]+sred[1]+sred[2]+sred[3]);
        float* cO = inp ? c2 : c1;
        #pragma unroll
        for (int i = 0; i < 4; ++i) {
            int mm = tid + i*256;
            if (mm < 800) {
                cO[(size_t)b*800 + mm] = qloc[i]*inv;
                if (inp == 0) d1[(size_t)b*800 + mm] = dloc[i];
            }
        }
        __syncthreads();   // protect red/sred reuse next iteration
    }
    if (tid == 0) {
        float ss = 0.f;
        #pragma unroll
        for (int j = 0; j < 10; ++j) {
            float df = se[0][j] - se[1][j] + 1e-6f;
            ss += df*df;
        }
        simOut[b] = sqrtf(ss);
    }
}

// ---------------------------------------------------------------------------
extern "C" void kernel_launch(void* const* d_in, const int* in_sizes, int n_in,
                              void* d_out, int out_size, void* d_ws, size_t ws_size,
                              hipStream_t stream)
{
    const float* x1 = (const float*)d_in[0];
    const float* x2 = (const float*)d_in[1];
    const float *W[5], *bi[5], *ga[5], *be[5];
    for (int l = 0; l < 5; l++) {
        W[l]  = (const float*)d_in[2 + 4*l];
        bi[l] = (const float*)d_in[3 + 4*l];
        ga[l] = (const float*)d_in[4 + 4*l];
        be[l] = (const float*)d_in[5 + 4*l];
    }
    const float* embW = (const float*)d_in[22];
    const float* embB = (const float*)d_in[23];
    const float* cluW = (const float*)d_in[24];
    float* out = (float*)d_out;
    float* ws  = (float*)d_ws;

    // workspace (floats for region bases; bf16 intermediates inside):
    //   stats 20480 | weights 73728 (bf16 x 147456)
    //   R1 = 8,388,608 floats : P0 bf16 [2*NROWS][64] (14.7MB) / osel bf16 (16.8MB)
    //   R2 = 14,680,064 floats: P1 bf16 / Q bf16 [2*NROWS][128] (first 7.34M fl)
    //                           part [1024][2048] fl (next 2.10M fl, 8MB)
    float*  stats = ws;
    __bf16* wt2   = (__bf16*)(ws + 20480);
    __bf16* wt3   = wt2 + 4096;
    __bf16* wt4   = wt2 + 8192;
    __bf16* wt5b  = wt2 + 16384;
    float*  R1f   = ws + 20480 + 73728;
    float*  R2f   = R1f + 8388608;
    __bf16* P0    = (__bf16*)R1f;
    __bf16* P1    = (__bf16*)R2f;
    __bf16* Q     = (__bf16*)R2f;    // overwrites P1 (dead after layer 3)
    __bf16* osel  = (__bf16*)R1f;    // overwrites P0 (dead after layer 4)
    float*  part  = R2f + 7340032;   // after Q, no overlap

    wprep_kernel<<<656, 256, 0, stream>>>(W[1], W[2], W[3], W[4],
                                          wt2, wt3, wt4, wt5b, stats);

    float* simO = out;
    float* c1O  = out + 4096;
    float* c2O  = out + 3280896;
    float* e1O  = out + 6557696;
    float* e2O  = out + 6598656;
    float* d1O  = out + 6639616;

    l1_kernel<<<2048, 256, 0, stream>>>(x1, x2, W[0], bi[0], P0, stats);
    layer_kernel<64><<<1024, 256, 0, stream>>>(
        P0, stats + 0,    ga[0], be[0], wt2, bi[1], P1, stats + 2048);
    layer_kernel<64><<<1024, 256, 0, stream>>>(
        P1, stats + 2048, ga[1], be[1], wt3, bi[2], P0, stats + 4096);
    layer_kernel<128><<<1024, 256, 0, stream>>>(
        P0, stats + 4096, ga[2], be[2], wt4, bi[3], Q, stats + 6144);
    l5_kernel<<<1024, 256, 0, stream>>>(
        Q, stats + 6144, ga[3], be[3], wt5b, bi[4], ga[4], osel, part);
    sreduce_kernel<<<16, 256, 0, stream>>>(part, stats);
    headclu_kernel<<<4096, 256, 0, stream>>>(
        osel, stats, ga[4], be[4], embW, embB, cluW,
        e1O, e2O, c1O, c2O, d1O, simO);
}

// Round 17
// 293.659 us; speedup vs baseline: 1.2624x; 1.2624x over previous
//
#include <hip/hip_runtime.h>
#include <hip/hip_bf16.h>

#define NB 4096
#define PLEN 14
#define NROWS (NB*PLEN)     // 57344 per input
#define BN_EPS 1e-5f

// stats layout (floats): input i at +i*133120.
//   slot L (L=0..3, banked): +L*32768, 16 banks x {1024 sums, 1024 sumsq}
//   slot 4 (flat, from sreduce): +131072, {1024 sums, 1024 sumsq}
#define SLOT_STRIDE 32768
#define INP_STRIDE  133120
#define SLOT5_OFF   131072
#define NBANK 16

typedef __bf16 bf16x8 __attribute__((ext_vector_type(8)));
typedef float  f32x4  __attribute__((ext_vector_type(4)));

// ---------------- wprep: zero stats + all weight converts in one launch ----
__global__ __launch_bounds__(256) void wprep_kernel(
    const float* __restrict__ W2, const float* __restrict__ W3,
    const float* __restrict__ W4, const float* __restrict__ W5,
    __bf16* __restrict__ wt2, __bf16* __restrict__ wt3,
    __bf16* __restrict__ wt4, __bf16* __restrict__ wt5b,
    float* __restrict__ stats)
{
    int idx = blockIdx.x*256 + threadIdx.x;
    if (idx < 2*INP_STRIDE) { stats[idx] = 0.f; return; }
    idx -= 2*INP_STRIDE;
    if (idx < 4096) { int n = idx>>6, k = idx&63; wt2[idx] = (__bf16)W2[k*64+n]; return; }
    idx -= 4096;
    if (idx < 4096) { int n = idx>>6, k = idx&63; wt3[idx] = (__bf16)W3[k*64+n]; return; }
    idx -= 4096;
    if (idx < 8192) { int n = idx>>6, k = idx&63; wt4[idx] = (__bf16)W4[k*128+n]; return; }
    idx -= 8192;
    // W5 blocked: [16 c][16 kg][64 n][8 kk]
    int kk = idx & 7, n = (idx >> 3) & 63, kg = (idx >> 9) & 15, c = idx >> 13;
    wt5b[idx] = (__bf16)W5[(kg*8 + kk)*1024 + c*64 + n];
}

// ---------------- Layer 1 (both inputs): agg(x) @ W1 + b1, stats ----------
// Stats via BANKED atomics (bank = blockIdx&15): same-address chain depth
// drops 1024 -> 64 (the round-16 diagnosis: l1 idle at 50us = atomic tail).
__global__ __launch_bounds__(256) void l1_kernel(
    const float* __restrict__ x1,    // [NB][3][PLEN]
    const float* __restrict__ x2,
    const float* __restrict__ W,     // [3][64]
    const float* __restrict__ bias,  // [64]
    __bf16* __restrict__ pre,        // [2*NROWS][64] bf16
    float* __restrict__ stats)       // base (slot0 banked)
{
    const int col  = threadIdx.x & 63;
    const int sub  = threadIdx.x >> 6;
    const int chain = blockIdx.x * 4 + sub;      // 0..8191 global
    const int inp  = chain >> 12;                // uniform per block
    const int bank = blockIdx.x & (NBANK-1);
    const float w0 = W[0*64+col], w1 = W[1*64+col], w2 = W[2*64+col];
    const float bb = bias[col];
    const float* xb = (inp ? x2 : x1) + (chain & 4095)*3*PLEN;
    float s = 0.f, s2 = 0.f;
    for (int p = 0; p < PLEN; p++) {
        float u0 = 0.f, u1 = 0.f, u2 = 0.f;
        if (p > 0)      { u0 += xb[p-1]; u1 += xb[PLEN+p-1]; u2 += xb[2*PLEN+p-1]; }
        if (p < PLEN-1) { u0 += xb[p+1]; u1 += xb[PLEN+p+1]; u2 += xb[2*PLEN+p+1]; }
        float v = u0*w0 + u1*w1 + u2*w2 + bb;
        pre[(size_t)(chain*PLEN + p)*64 + col] = (__bf16)v;
        s += v; s2 += v*v;
    }
    __shared__ float ss[4][64], ssq[4][64];
    ss[sub][col] = s; ssq[sub][col] = s2;
    __syncthreads();
    if (sub == 0) {
        float ts  = ss[0][col]+ss[1][col]+ss[2][col]+ss[3][col];
        float ts2 = ssq[0][col]+ssq[1][col]+ssq[2][col]+ssq[3][col];
        float* st = stats + inp*INP_STRIDE + bank*2048;
        atomicAdd(&st[col], ts);
        atomicAdd(&st[1024 + col], ts2);
    }
}

// ---------------- fused layer (2-4), both inputs: BN+ReLU+agg -> GEMM -----
// bf16 intermediates; B in registers; BANKED stats in AND out.
template<int NOUT>
__global__ __launch_bounds__(256) void layer_kernel(
    const __bf16* __restrict__ prev,     // [2*NROWS][64] bf16
    const float* __restrict__ stats_in,  // input-0 slot base (banked)
    const float* __restrict__ gamma, const float* __restrict__ beta,
    const __bf16* __restrict__ wt,       // [NOUT][64]
    const float* __restrict__ bias,      // [NOUT]
    __bf16* __restrict__ outp,           // [2*NROWS][NOUT] bf16
    float* __restrict__ stats_out)       // input-0 slot base (banked)
{
    constexpr int KP = 72;
    constexpr int NCH = NOUT/64;
    __shared__ __align__(16) short sA[112*KP];
    const int tid = threadIdx.x, wave = tid >> 6, lane = tid & 63;
    const int m = lane & 15, q = lane >> 4;
    const int rowbase = blockIdx.x * 112;            // global over 114688 rows
    const int soff = (blockIdx.x >> 9) * INP_STRIDE; // input select (512 blocks/input)
    const int bank = blockIdx.x & (NBANK-1);
    const float* sin_ = stats_in + soff;

    // B -> registers (L2-hot, 8/16 KB total)
    bf16x8 breg[NCH][2];
    #pragma unroll
    for (int cc = 0; cc < NCH; ++cc)
        #pragma unroll
        for (int ksi = 0; ksi < 2; ++ksi)
            breg[cc][ksi] = *reinterpret_cast<const bf16x8*>(
                wt + (cc*64 + wave*16 + m)*64 + ksi*32 + q*8);

    // build A = chain_agg(relu(bn(prev))): thread owns 1 chain x 2 cols
    {
        const int ch = tid >> 5, c2 = (tid & 31)*2;
        float s0 = 0.f, q0 = 0.f, s1 = 0.f, q1 = 0.f;
        #pragma unroll
        for (int bk = 0; bk < NBANK; ++bk) {
            s0 += sin_[bk*2048 + c2];
            q0 += sin_[bk*2048 + 1024 + c2];
            s1 += sin_[bk*2048 + c2 + 1];
            q1 += sin_[bk*2048 + 1024 + c2 + 1];
        }
        float mu0 = s0*(1.f/NROWS);
        float v0  = q0*(1.f/NROWS) - mu0*mu0;
        float a0  = gamma[c2]*rsqrtf(v0+BN_EPS), c0 = beta[c2]-mu0*a0;
        float mu1 = s1*(1.f/NROWS);
        float v1  = q1*(1.f/NROWS) - mu1*mu1;
        float a1  = gamma[c2+1]*rsqrtf(v1+BN_EPS), c1 = beta[c2+1]-mu1*a1;
        float h0[14], h1[14];
        const __bf16* src = prev + (size_t)(rowbase + ch*14)*64 + c2;
        #pragma unroll
        for (int r = 0; r < 14; ++r) {
            union { unsigned u; __bf16 b[2]; } ld;
            ld.u = *reinterpret_cast<const unsigned*>(src + r*64);
            h0[r] = fmaxf(a0*(float)ld.b[0] + c0, 0.f);
            h1[r] = fmaxf(a1*(float)ld.b[1] + c1, 0.f);
        }
        #pragma unroll
        for (int r = 0; r < 14; ++r) {
            float g0 = (r>0 ? h0[r-1] : 0.f) + (r<13 ? h0[r+1] : 0.f);
            float g1 = (r>0 ? h1[r-1] : 0.f) + (r<13 ? h1[r+1] : 0.f);
            union { __bf16 b[2]; unsigned u; } pk;
            pk.b[0] = (__bf16)g0; pk.b[1] = (__bf16)g1;
            *reinterpret_cast<unsigned*>(&sA[(ch*14+r)*KP + c2]) = pk.u;
        }
    }
    __syncthreads();

    f32x4 acc[NCH][7];
    #pragma unroll
    for (int cc = 0; cc < NCH; ++cc)
        #pragma unroll
        for (int t = 0; t < 7; ++t) acc[cc][t] = (f32x4){0.f,0.f,0.f,0.f};

    #pragma unroll
    for (int ksi = 0; ksi < 2; ++ksi) {
        bf16x8 af[7];
        #pragma unroll
        for (int t = 0; t < 7; ++t)
            af[t] = *reinterpret_cast<const bf16x8*>(&sA[(t*16+m)*KP + ksi*32 + q*8]);
        #pragma unroll
        for (int cc = 0; cc < NCH; ++cc)
            #pragma unroll
            for (int t = 0; t < 7; ++t)
                acc[cc][t] = __builtin_amdgcn_mfma_f32_16x16x32_bf16(af[t], breg[cc][ksi], acc[cc][t], 0, 0, 0);
    }

    float* stout = stats_out + soff + bank*2048;
    #pragma unroll
    for (int cc = 0; cc < NCH; ++cc) {
        const int ocol = cc*64 + wave*16 + m;
        const float bb = bias[ocol];
        float s = 0.f, s2 = 0.f;
        #pragma unroll
        for (int t = 0; t < 7; ++t)
            #pragma unroll
            for (int r = 0; r < 4; ++r) {
                float v = acc[cc][t][r] + bb;
                outp[(size_t)(rowbase + t*16 + q*4 + r)*NOUT + ocol] = (__bf16)v;
                s += v; s2 += v*v;
            }
        s  += __shfl_xor(s, 16);  s  += __shfl_xor(s, 32);
        s2 += __shfl_xor(s2, 16); s2 += __shfl_xor(s2, 32);
        if (lane < 16) {
            atomicAdd(&stout[ocol], s);
            atomicAdd(&stout[1024 + ocol], s2);
        }
    }
}

// ---------------- Layer 5 (both inputs), 256 threads / 4 waves -------------
// Barrier-free main loop, B streamed through registers, bf16 in/out.
// BANKED stats in (slot3); partial-store stats out (validated round 16).
__global__ __launch_bounds__(256, 1) void l5_kernel(
    const __bf16* __restrict__ prev,     // [2*NROWS][128] bf16 (pre4)
    const float* __restrict__ stats_in,  // input-0 slot3 base (banked)
    const float* __restrict__ gamma, const float* __restrict__ beta,
    const __bf16* __restrict__ wtb,      // blocked W5: [16 c][16 kg][64 n][8 kk]
    const float* __restrict__ bias,      // [1024]
    const float* __restrict__ g5,        // gamma5 [1024] (sign select)
    __bf16* __restrict__ osel,           // [2*NB][1024] bf16
    float* __restrict__ part)            // [1024 blocks][2048] partial stats
{
    __shared__ __align__(16) short sA[112*136];   // 30464 B, permuted A rows
    const int tid = threadIdx.x, wave = tid >> 6, lane = tid & 63;
    const int m = lane & 15, q = lane >> 4;
    const int rowbase = blockIdx.x * 112;
    const int soff = (blockIdx.x >> 9) * INP_STRIDE;
    const float* sin_ = stats_in + soff;
    float* pb = part + (size_t)blockIdx.x * 2048;

    // per-lane B offset within a 16KB chunk, in BYTES: kg = k4*4+q (stride
    // 1024 B), n = wave*16+m (stride 16 B); k4 stride = 4 kg = 4096 B.
    const char* gw = (const char*)wtb;
    const int boffB = q*1024 + (wave*16 + m)*16;

    // prefetch B chunk 0 into registers (covered by A staging below)
    bf16x8 bA[4], bB[4];
    #pragma unroll
    for (int k4 = 0; k4 < 4; ++k4)
        bA[k4] = *reinterpret_cast<const bf16x8*>(gw + boffB + k4*4096);

    // build A = chain_agg(relu(bn(pre4))), PERMUTED rows: thread owns 1 chain x 4 cols
    {
        const int ch = tid >> 5, c4 = (tid & 31)*4;
        float aa[4], cc4[4];
        #pragma unroll
        for (int j = 0; j < 4; ++j) {
            float sb = 0.f, qb = 0.f;
            #pragma unroll
            for (int bk = 0; bk < NBANK; ++bk) {
                sb += sin_[bk*2048 + c4+j];
                qb += sin_[bk*2048 + 1024 + c4+j];
            }
            float mu = sb*(1.f/NROWS);
            float vr = qb*(1.f/NROWS) - mu*mu;
            aa[j] = gamma[c4+j]*rsqrtf(vr+BN_EPS);
            cc4[j] = beta[c4+j] - mu*aa[j];
        }
        float h[14][4];
        const __bf16* src = prev + (size_t)(rowbase + ch*14)*128 + c4;
        #pragma unroll
        for (int r = 0; r < 14; ++r) {
            union { uint2 u; __bf16 b[4]; } ld;
            ld.u = *reinterpret_cast<const uint2*>(src + r*128);
            h[r][0] = fmaxf(aa[0]*(float)ld.b[0] + cc4[0], 0.f);
            h[r][1] = fmaxf(aa[1]*(float)ld.b[1] + cc4[1], 0.f);
            h[r][2] = fmaxf(aa[2]*(float)ld.b[2] + cc4[2], 0.f);
            h[r][3] = fmaxf(aa[3]*(float)ld.b[3] + cc4[3], 0.f);
        }
        const int qq = ch >> 1, jb = (ch & 1) * 14;
        #pragma unroll
        for (int p = 0; p < 14; ++p) {
            int j = jb + p;
            int slot = (j>>2)*16 + qq*4 + (j&3);
            union { __bf16 b[4]; uint2 u; } pk;
            #pragma unroll
            for (int jj = 0; jj < 4; ++jj) {
                float g = (p>0 ? h[p-1][jj] : 0.f) + (p<13 ? h[p+1][jj] : 0.f);
                pk.b[jj] = (__bf16)g;
            }
            *reinterpret_cast<uint2*>(&sA[slot*136 + c4]) = pk.u;
        }
    }
    __syncthreads();   // the ONLY barrier: sA complete

    // A fragments -> registers (sA never touched again)
    bf16x8 af[7][4];
    #pragma unroll
    for (int t = 0; t < 7; ++t)
        #pragma unroll
        for (int kk = 0; kk < 4; ++kk)
            af[t][kk] = *reinterpret_cast<const bf16x8*>(&sA[(t*16 + m)*136 + kk*32 + q*8]);

    // one c-step: MFMA from bR, epilogue (register chain-max + partial store)
    auto step = [&](int c, bf16x8 (&bR)[4]) {
        f32x4 acc[7];
        #pragma unroll
        for (int t = 0; t < 7; ++t) acc[t] = (f32x4){0.f,0.f,0.f,0.f};
        #pragma unroll
        for (int k4 = 0; k4 < 4; ++k4)
            #pragma unroll
            for (int t = 0; t < 7; ++t)
                acc[t] = __builtin_amdgcn_mfma_f32_16x16x32_bf16(af[t][k4], bR[k4], acc[t], 0, 0, 0);
        const int ocol = c*64 + wave*16 + m;
        const float bb = bias[ocol];
        const float sg = (g5[ocol] >= 0.f) ? 1.f : -1.f;
        float s = 0.f, s2 = 0.f;
        float mx0 = -3.4e38f, mx1 = -3.4e38f;
        #pragma unroll
        for (int t = 0; t < 7; ++t)
            #pragma unroll
            for (int r = 0; r < 4; ++r) {
                float v = acc[t][r] + bb;
                s += v; s2 += v*v;
                float va = sg * v;
                if (t*4 + r < 14) mx0 = fmaxf(mx0, va);
                else              mx1 = fmaxf(mx1, va);
            }
        osel[(size_t)(blockIdx.x*8 + 2*q    )*1024 + ocol] = (__bf16)(sg * mx0);
        osel[(size_t)(blockIdx.x*8 + 2*q + 1)*1024 + ocol] = (__bf16)(sg * mx1);
        s  += __shfl_xor(s, 16);  s  += __shfl_xor(s, 32);
        s2 += __shfl_xor(s2, 16); s2 += __shfl_xor(s2, 32);
        if (lane < 16) {
            pb[ocol]        = s;    // plain stores — summed by sreduce_kernel
            pb[1024 + ocol] = s2;
        }
    };

    #pragma unroll 1
    for (int cc = 0; cc < 16; cc += 2) {
        // even step: prefetch chunk cc+1 -> bB, compute cc from bA
        {
            const char* gb = gw + (size_t)(cc+1)*16384 + boffB;   // BYTES
            #pragma unroll
            for (int k4 = 0; k4 < 4; ++k4)
                bB[k4] = *reinterpret_cast<const bf16x8*>(gb + k4*4096);
        }
        step(cc, bA);
        // odd step: prefetch chunk cc+2 -> bA, compute cc+1 from bB
        if (cc + 2 < 16) {
            const char* gb = gw + (size_t)(cc+2)*16384 + boffB;   // BYTES
            #pragma unroll
            for (int k4 = 0; k4 < 4; ++k4)
                bA[k4] = *reinterpret_cast<const bf16x8*>(gb + k4*4096);
        }
        step(cc + 1, bB);
    }
}

// ---------------- sreduce: sum l5 partials -> flat slot4 ------------------
__global__ __launch_bounds__(256) void sreduce_kernel(
    const float* __restrict__ part, float* __restrict__ stats)
{
    const int cg  = blockIdx.x*256 + threadIdx.x;   // 0..4095
    const int inp = cg >> 11;
    const int col = cg & 2047;
    const float* p = part + (size_t)inp*512*2048 + col;
    float s = 0.f;
    #pragma unroll 4
    for (int b = 0; b < 512; ++b)
        s += p[(size_t)b*2048];
    stats[inp*INP_STRIDE + SLOT5_OFF + col] = s;
}

// ---------------- head+cluster fused, both inputs: one block per batch row -
__global__ __launch_bounds__(256) void headclu_kernel(
    const __bf16* __restrict__ osel,  // [2*NB][1024] bf16
    const float* __restrict__ stats,  // base
    const float* __restrict__ gamma, const float* __restrict__ beta,
    const float* __restrict__ embW, const float* __restrict__ embB,
    const float* __restrict__ cluW,
    float* __restrict__ e1, float* __restrict__ e2,
    float* __restrict__ c1, float* __restrict__ c2,
    float* __restrict__ d1, float* __restrict__ simOut)
{
    const int b = blockIdx.x, tid = threadIdx.x;
    const int wave = tid >> 6, lane = tid & 63;
    __shared__ float red[4][10];
    __shared__ float se[2][10];
    __shared__ float sred[4];

    for (int inp = 0; inp < 2; ++inp) {
        const float* st  = stats + inp*INP_STRIDE + SLOT5_OFF;
        const __bf16* row = osel + (size_t)(inp*NB + b)*1024;
        float acc[10];
        #pragma unroll
        for (int j = 0; j < 10; ++j) acc[j] = 0.f;
        #pragma unroll
        for (int i = 0; i < 4; ++i) {
            int k = tid + i*256;
            float mu  = st[k]*(1.f/NROWS);
            float var = st[1024+k]*(1.f/NROWS) - mu*mu;
            float a = gamma[k]*rsqrtf(var+BN_EPS);
            float c = beta[k] - mu*a;
            float h = fmaxf(a*(float)row[k] + c, 0.f);
            #pragma unroll
            for (int j = 0; j < 10; ++j) acc[j] += h * embW[k*10 + j];
        }
        #pragma unroll
        for (int j = 0; j < 10; ++j) {
            acc[j] += __shfl_down(acc[j], 32);
            acc[j] += __shfl_down(acc[j], 16);
            acc[j] += __shfl_down(acc[j], 8);
            acc[j] += __shfl_down(acc[j], 4);
            acc[j] += __shfl_down(acc[j], 2);
            acc[j] += __shfl_down(acc[j], 1);
        }
        if (lane == 0)
            #pragma unroll
            for (int j = 0; j < 10; ++j) red[wave][j] = acc[j];
        __syncthreads();
        if (tid < 10) {
            float t = red[0][tid]+red[1][tid]+red[2][tid]+red[3][tid] + embB[tid];
            se[inp][tid] = t;
            (inp ? e2 : e1)[b*10 + tid] = t;
        }
        __syncthreads();

        float ev[10];
        #pragma unroll
        for (int j = 0; j < 10; ++j) ev[j] = se[inp][j];
        float dloc[4], qloc[4], qs = 0.f;
        #pragma unroll
        for (int i = 0; i < 4; ++i) {
            int mm = tid + i*256;
            float dd = 0.f;
            if (mm < 800) {
                #pragma unroll
                for (int j = 0; j < 10; ++j) { float t = ev[j] - cluW[mm*10 + j]; dd += t*t; }
            }
            dloc[i] = dd;
            float qv = (mm < 800) ? 1.f/(1.f + dd) : 0.f;
            qloc[i] = qv; qs += qv;
        }
        float t = qs;
        t += __shfl_down(t,32); t += __shfl_down(t,16); t += __shfl_down(t,8);
        t += __shfl_down(t,4);  t += __shfl_down(t,2);  t += __shfl_down(t,1);
        if (lane == 0) sred[wave] = t;
        __syncthreads();
        float inv = 1.f / (sred[0]+sred[1]+sred[2]+sred[3]);
        float* cO = inp ? c2 : c1;
        #pragma unroll
        for (int i = 0; i < 4; ++i) {
            int mm = tid + i*256;
            if (mm < 800) {
                cO[(size_t)b*800 + mm] = qloc[i]*inv;
                if (inp == 0) d1[(size_t)b*800 + mm] = dloc[i];
            }
        }
        __syncthreads();   // protect red/sred reuse next iteration
    }
    if (tid == 0) {
        float ss = 0.f;
        #pragma unroll
        for (int j = 0; j < 10; ++j) {
            float df = se[0][j] - se[1][j] + 1e-6f;
            ss += df*df;
        }
        simOut[b] = sqrtf(ss);
    }
}

// ---------------------------------------------------------------------------
extern "C" void kernel_launch(void* const* d_in, const int* in_sizes, int n_in,
                              void* d_out, int out_size, void* d_ws, size_t ws_size,
                              hipStream_t stream)
{
    const float* x1 = (const float*)d_in[0];
    const float* x2 = (const float*)d_in[1];
    const float *W[5], *bi[5], *ga[5], *be[5];
    for (int l = 0; l < 5; l++) {
        W[l]  = (const float*)d_in[2 + 4*l];
        bi[l] = (const float*)d_in[3 + 4*l];
        ga[l] = (const float*)d_in[4 + 4*l];
        be[l] = (const float*)d_in[5 + 4*l];
    }
    const float* embW = (const float*)d_in[22];
    const float* embB = (const float*)d_in[23];
    const float* cluW = (const float*)d_in[24];
    float* out = (float*)d_out;
    float* ws  = (float*)d_ws;

    // workspace (floats):
    //   stats 266240 (2 x 133120) | weights 73728 (bf16 x 147456)
    //   R1 = 8,388,608 : P0 bf16 [2*NROWS][64] / osel bf16 [2*NB][1024]
    //   R2 = 14,680,064: P1/Q bf16 [2*NROWS][128] (7.34M fl) + part 2.10M fl
    // total ~23.4M floats = 93.6 MB
    float*  stats = ws;
    __bf16* wt2   = (__bf16*)(ws + 2*INP_STRIDE);
    __bf16* wt3   = wt2 + 4096;
    __bf16* wt4   = wt2 + 8192;
    __bf16* wt5b  = wt2 + 16384;
    float*  R1f   = ws + 2*INP_STRIDE + 73728;
    float*  R2f   = R1f + 8388608;
    __bf16* P0    = (__bf16*)R1f;
    __bf16* P1    = (__bf16*)R2f;
    __bf16* Q     = (__bf16*)R2f;    // overwrites P1 (dead after layer 3)
    __bf16* osel  = (__bf16*)R1f;    // overwrites P0 (dead after layer 4)
    float*  part  = R2f + 7340032;   // after Q, no overlap

    // grid: zero 266240 + convert 147456 = 413696 items -> 1616 blocks
    wprep_kernel<<<1616, 256, 0, stream>>>(W[1], W[2], W[3], W[4],
                                           wt2, wt3, wt4, wt5b, stats);

    float* simO = out;
    float* c1O  = out + 4096;
    float* c2O  = out + 3280896;
    float* e1O  = out + 6557696;
    float* e2O  = out + 6598656;
    float* d1O  = out + 6639616;

    l1_kernel<<<2048, 256, 0, stream>>>(x1, x2, W[0], bi[0], P0, stats);
    layer_kernel<64><<<1024, 256, 0, stream>>>(
        P0, stats + 0*SLOT_STRIDE, ga[0], be[0], wt2, bi[1], P1, stats + 1*SLOT_STRIDE);
    layer_kernel<64><<<1024, 256, 0, stream>>>(
        P1, stats + 1*SLOT_STRIDE, ga[1], be[1], wt3, bi[2], P0, stats + 2*SLOT_STRIDE);
    layer_kernel<128><<<1024, 256, 0, stream>>>(
        P0, stats + 2*SLOT_STRIDE, ga[2], be[2], wt4, bi[3], Q, stats + 3*SLOT_STRIDE);
    l5_kernel<<<1024, 256, 0, stream>>>(
        Q, stats + 3*SLOT_STRIDE, ga[3], be[3], wt5b, bi[4], ga[4], osel, part);
    sreduce_kernel<<<16, 256, 0, stream>>>(part, stats);
    headclu_kernel<<<4096, 256, 0, stream>>>(
        osel, stats, ga[4], be[4], embW, embB, cluW,
        e1O, e2O, c1O, c2O, d1O, simO);
}

// Round 18
// 288.019 us; speedup vs baseline: 1.2871x; 1.0196x over previous
//
#include <hip/hip_runtime.h>
#include <hip/hip_bf16.h>

#define NB 4096
#define PLEN 14
#define NROWS (NB*PLEN)     // 57344 per input
#define BN_EPS 1e-5f

// stats layout (floats): input i at +i*133120.
//   slot L (L=0..3, banked): +L*32768, 16 banks x {1024 sums, 1024 sumsq}
//   slot 4 (flat, from sreduce): +131072, {1024 sums, 1024 sumsq}
#define SLOT_STRIDE 32768
#define INP_STRIDE  133120
#define SLOT5_OFF   131072
#define NBANK 16

typedef __bf16 bf16x8 __attribute__((ext_vector_type(8)));
typedef float  f32x4  __attribute__((ext_vector_type(4)));

// ---------------- wprep: zero stats + all weight converts in one launch ----
__global__ __launch_bounds__(256) void wprep_kernel(
    const float* __restrict__ W2, const float* __restrict__ W3,
    const float* __restrict__ W4, const float* __restrict__ W5,
    __bf16* __restrict__ wt2, __bf16* __restrict__ wt3,
    __bf16* __restrict__ wt4, __bf16* __restrict__ wt5b,
    float* __restrict__ stats)
{
    int idx = blockIdx.x*256 + threadIdx.x;
    if (idx < 2*INP_STRIDE) { stats[idx] = 0.f; return; }
    idx -= 2*INP_STRIDE;
    if (idx < 4096) { int n = idx>>6, k = idx&63; wt2[idx] = (__bf16)W2[k*64+n]; return; }
    idx -= 4096;
    if (idx < 4096) { int n = idx>>6, k = idx&63; wt3[idx] = (__bf16)W3[k*64+n]; return; }
    idx -= 4096;
    if (idx < 8192) { int n = idx>>6, k = idx&63; wt4[idx] = (__bf16)W4[k*128+n]; return; }
    idx -= 8192;
    // W5 blocked: [16 c][16 kg][64 n][8 kk]
    int kk = idx & 7, n = (idx >> 3) & 63, kg = (idx >> 9) & 15, c = idx >> 13;
    wt5b[idx] = (__bf16)W5[(kg*8 + kk)*1024 + c*64 + n];
}

// ---------------- Layer 1 (both inputs): agg(x) @ W1 + b1, stats ----------
// Stats via BANKED atomics (bank = blockIdx&15): chain depth 1024 -> 64.
__global__ __launch_bounds__(256) void l1_kernel(
    const float* __restrict__ x1,    // [NB][3][PLEN]
    const float* __restrict__ x2,
    const float* __restrict__ W,     // [3][64]
    const float* __restrict__ bias,  // [64]
    __bf16* __restrict__ pre,        // [2*NROWS][64] bf16
    float* __restrict__ stats)       // base (slot0 banked)
{
    const int col  = threadIdx.x & 63;
    const int sub  = threadIdx.x >> 6;
    const int chain = blockIdx.x * 4 + sub;      // 0..8191 global
    const int inp  = chain >> 12;                // uniform per block
    const int bank = blockIdx.x & (NBANK-1);
    const float w0 = W[0*64+col], w1 = W[1*64+col], w2 = W[2*64+col];
    const float bb = bias[col];
    const float* xb = (inp ? x2 : x1) + (chain & 4095)*3*PLEN;
    float s = 0.f, s2 = 0.f;
    for (int p = 0; p < PLEN; p++) {
        float u0 = 0.f, u1 = 0.f, u2 = 0.f;
        if (p > 0)      { u0 += xb[p-1]; u1 += xb[PLEN+p-1]; u2 += xb[2*PLEN+p-1]; }
        if (p < PLEN-1) { u0 += xb[p+1]; u1 += xb[PLEN+p+1]; u2 += xb[2*PLEN+p+1]; }
        float v = u0*w0 + u1*w1 + u2*w2 + bb;
        pre[(size_t)(chain*PLEN + p)*64 + col] = (__bf16)v;
        s += v; s2 += v*v;
    }
    __shared__ float ss[4][64], ssq[4][64];
    ss[sub][col] = s; ssq[sub][col] = s2;
    __syncthreads();
    if (sub == 0) {
        float ts  = ss[0][col]+ss[1][col]+ss[2][col]+ss[3][col];
        float ts2 = ssq[0][col]+ssq[1][col]+ssq[2][col]+ssq[3][col];
        float* st = stats + inp*INP_STRIDE + bank*2048;
        atomicAdd(&st[col], ts);
        atomicAdd(&st[1024 + col], ts2);
    }
}

// ---------------- fused layer (2-4), both inputs: BN+ReLU+agg -> GEMM -----
// bf16 intermediates; B in registers; BANKED stats in AND out.
template<int NOUT>
__global__ __launch_bounds__(256) void layer_kernel(
    const __bf16* __restrict__ prev,     // [2*NROWS][64] bf16
    const float* __restrict__ stats_in,  // input-0 slot base (banked)
    const float* __restrict__ gamma, const float* __restrict__ beta,
    const __bf16* __restrict__ wt,       // [NOUT][64]
    const float* __restrict__ bias,      // [NOUT]
    __bf16* __restrict__ outp,           // [2*NROWS][NOUT] bf16
    float* __restrict__ stats_out)       // input-0 slot base (banked)
{
    constexpr int KP = 72;
    constexpr int NCH = NOUT/64;
    __shared__ __align__(16) short sA[112*KP];
    const int tid = threadIdx.x, wave = tid >> 6, lane = tid & 63;
    const int m = lane & 15, q = lane >> 4;
    const int rowbase = blockIdx.x * 112;            // global over 114688 rows
    const int soff = (blockIdx.x >> 9) * INP_STRIDE; // input select (512 blocks/input)
    const int bank = blockIdx.x & (NBANK-1);
    const float* sin_ = stats_in + soff;

    // B -> registers (L2-hot, 8/16 KB total)
    bf16x8 breg[NCH][2];
    #pragma unroll
    for (int cc = 0; cc < NCH; ++cc)
        #pragma unroll
        for (int ksi = 0; ksi < 2; ++ksi)
            breg[cc][ksi] = *reinterpret_cast<const bf16x8*>(
                wt + (cc*64 + wave*16 + m)*64 + ksi*32 + q*8);

    // build A = chain_agg(relu(bn(prev))): thread owns 1 chain x 2 cols
    {
        const int ch = tid >> 5, c2 = (tid & 31)*2;
        float s0 = 0.f, q0 = 0.f, s1 = 0.f, q1 = 0.f;
        #pragma unroll
        for (int bk = 0; bk < NBANK; ++bk) {
            s0 += sin_[bk*2048 + c2];
            q0 += sin_[bk*2048 + 1024 + c2];
            s1 += sin_[bk*2048 + c2 + 1];
            q1 += sin_[bk*2048 + 1024 + c2 + 1];
        }
        float mu0 = s0*(1.f/NROWS);
        float v0  = q0*(1.f/NROWS) - mu0*mu0;
        float a0  = gamma[c2]*rsqrtf(v0+BN_EPS), c0 = beta[c2]-mu0*a0;
        float mu1 = s1*(1.f/NROWS);
        float v1  = q1*(1.f/NROWS) - mu1*mu1;
        float a1  = gamma[c2+1]*rsqrtf(v1+BN_EPS), c1 = beta[c2+1]-mu1*a1;
        float h0[14], h1[14];
        const __bf16* src = prev + (size_t)(rowbase + ch*14)*64 + c2;
        #pragma unroll
        for (int r = 0; r < 14; ++r) {
            union { unsigned u; __bf16 b[2]; } ld;
            ld.u = *reinterpret_cast<const unsigned*>(src + r*64);
            h0[r] = fmaxf(a0*(float)ld.b[0] + c0, 0.f);
            h1[r] = fmaxf(a1*(float)ld.b[1] + c1, 0.f);
        }
        #pragma unroll
        for (int r = 0; r < 14; ++r) {
            float g0 = (r>0 ? h0[r-1] : 0.f) + (r<13 ? h0[r+1] : 0.f);
            float g1 = (r>0 ? h1[r-1] : 0.f) + (r<13 ? h1[r+1] : 0.f);
            union { __bf16 b[2]; unsigned u; } pk;
            pk.b[0] = (__bf16)g0; pk.b[1] = (__bf16)g1;
            *reinterpret_cast<unsigned*>(&sA[(ch*14+r)*KP + c2]) = pk.u;
        }
    }
    __syncthreads();

    f32x4 acc[NCH][7];
    #pragma unroll
    for (int cc = 0; cc < NCH; ++cc)
        #pragma unroll
        for (int t = 0; t < 7; ++t) acc[cc][t] = (f32x4){0.f,0.f,0.f,0.f};

    #pragma unroll
    for (int ksi = 0; ksi < 2; ++ksi) {
        bf16x8 af[7];
        #pragma unroll
        for (int t = 0; t < 7; ++t)
            af[t] = *reinterpret_cast<const bf16x8*>(&sA[(t*16+m)*KP + ksi*32 + q*8]);
        #pragma unroll
        for (int cc = 0; cc < NCH; ++cc)
            #pragma unroll
            for (int t = 0; t < 7; ++t)
                acc[cc][t] = __builtin_amdgcn_mfma_f32_16x16x32_bf16(af[t], breg[cc][ksi], acc[cc][t], 0, 0, 0);
    }

    float* stout = stats_out + soff + bank*2048;
    #pragma unroll
    for (int cc = 0; cc < NCH; ++cc) {
        const int ocol = cc*64 + wave*16 + m;
        const float bb = bias[ocol];
        float s = 0.f, s2 = 0.f;
        #pragma unroll
        for (int t = 0; t < 7; ++t)
            #pragma unroll
            for (int r = 0; r < 4; ++r) {
                float v = acc[cc][t][r] + bb;
                outp[(size_t)(rowbase + t*16 + q*4 + r)*NOUT + ocol] = (__bf16)v;
                s += v; s2 += v*v;
            }
        s  += __shfl_xor(s, 16);  s  += __shfl_xor(s, 32);
        s2 += __shfl_xor(s2, 16); s2 += __shfl_xor(s2, 32);
        if (lane < 16) {
            atomicAdd(&stout[ocol], s);
            atomicAdd(&stout[1024 + ocol], s2);
        }
    }
}

// ---------------- Layer 5 (both inputs), 256 threads / 4 waves -------------
// Barrier-free main loop, B streamed through registers, bf16 in/out.
// BANKED stats in (slot3); partial-store stats out (validated round 16).
__global__ __launch_bounds__(256, 1) void l5_kernel(
    const __bf16* __restrict__ prev,     // [2*NROWS][128] bf16 (pre4)
    const float* __restrict__ stats_in,  // input-0 slot3 base (banked)
    const float* __restrict__ gamma, const float* __restrict__ beta,
    const __bf16* __restrict__ wtb,      // blocked W5: [16 c][16 kg][64 n][8 kk]
    const float* __restrict__ bias,      // [1024]
    const float* __restrict__ g5,        // gamma5 [1024] (sign select)
    __bf16* __restrict__ osel,           // [2*NB][1024] bf16
    float* __restrict__ part)            // [1024 blocks][2048] partial stats
{
    __shared__ __align__(16) short sA[112*136];   // 30464 B, permuted A rows
    const int tid = threadIdx.x, wave = tid >> 6, lane = tid & 63;
    const int m = lane & 15, q = lane >> 4;
    const int rowbase = blockIdx.x * 112;
    const int soff = (blockIdx.x >> 9) * INP_STRIDE;
    const float* sin_ = stats_in + soff;
    float* pb = part + (size_t)blockIdx.x * 2048;

    // per-lane B offset within a 16KB chunk, in BYTES: kg = k4*4+q (stride
    // 1024 B), n = wave*16+m (stride 16 B); k4 stride = 4 kg = 4096 B.
    const char* gw = (const char*)wtb;
    const int boffB = q*1024 + (wave*16 + m)*16;

    // prefetch B chunk 0 into registers (covered by A staging below)
    bf16x8 bA[4], bB[4];
    #pragma unroll
    for (int k4 = 0; k4 < 4; ++k4)
        bA[k4] = *reinterpret_cast<const bf16x8*>(gw + boffB + k4*4096);

    // build A = chain_agg(relu(bn(pre4))), PERMUTED rows: thread owns 1 chain x 4 cols
    {
        const int ch = tid >> 5, c4 = (tid & 31)*4;
        float aa[4], cc4[4];
        #pragma unroll
        for (int j = 0; j < 4; ++j) {
            float sb = 0.f, qb = 0.f;
            #pragma unroll
            for (int bk = 0; bk < NBANK; ++bk) {
                sb += sin_[bk*2048 + c4+j];
                qb += sin_[bk*2048 + 1024 + c4+j];
            }
            float mu = sb*(1.f/NROWS);
            float vr = qb*(1.f/NROWS) - mu*mu;
            aa[j] = gamma[c4+j]*rsqrtf(vr+BN_EPS);
            cc4[j] = beta[c4+j] - mu*aa[j];
        }
        float h[14][4];
        const __bf16* src = prev + (size_t)(rowbase + ch*14)*128 + c4;
        #pragma unroll
        for (int r = 0; r < 14; ++r) {
            union { uint2 u; __bf16 b[4]; } ld;
            ld.u = *reinterpret_cast<const uint2*>(src + r*128);
            h[r][0] = fmaxf(aa[0]*(float)ld.b[0] + cc4[0], 0.f);
            h[r][1] = fmaxf(aa[1]*(float)ld.b[1] + cc4[1], 0.f);
            h[r][2] = fmaxf(aa[2]*(float)ld.b[2] + cc4[2], 0.f);
            h[r][3] = fmaxf(aa[3]*(float)ld.b[3] + cc4[3], 0.f);
        }
        const int qq = ch >> 1, jb = (ch & 1) * 14;
        #pragma unroll
        for (int p = 0; p < 14; ++p) {
            int j = jb + p;
            int slot = (j>>2)*16 + qq*4 + (j&3);
            union { __bf16 b[4]; uint2 u; } pk;
            #pragma unroll
            for (int jj = 0; jj < 4; ++jj) {
                float g = (p>0 ? h[p-1][jj] : 0.f) + (p<13 ? h[p+1][jj] : 0.f);
                pk.b[jj] = (__bf16)g;
            }
            *reinterpret_cast<uint2*>(&sA[slot*136 + c4]) = pk.u;
        }
    }
    __syncthreads();   // the ONLY barrier: sA complete

    // A fragments -> registers (sA never touched again)
    bf16x8 af[7][4];
    #pragma unroll
    for (int t = 0; t < 7; ++t)
        #pragma unroll
        for (int kk = 0; kk < 4; ++kk)
            af[t][kk] = *reinterpret_cast<const bf16x8*>(&sA[(t*16 + m)*136 + kk*32 + q*8]);

    // one c-step: MFMA from bR, epilogue (register chain-max + partial store)
    auto step = [&](int c, bf16x8 (&bR)[4]) {
        f32x4 acc[7];
        #pragma unroll
        for (int t = 0; t < 7; ++t) acc[t] = (f32x4){0.f,0.f,0.f,0.f};
        #pragma unroll
        for (int k4 = 0; k4 < 4; ++k4)
            #pragma unroll
            for (int t = 0; t < 7; ++t)
                acc[t] = __builtin_amdgcn_mfma_f32_16x16x32_bf16(af[t][k4], bR[k4], acc[t], 0, 0, 0);
        const int ocol = c*64 + wave*16 + m;
        const float bb = bias[ocol];
        const float sg = (g5[ocol] >= 0.f) ? 1.f : -1.f;
        float s = 0.f, s2 = 0.f;
        float mx0 = -3.4e38f, mx1 = -3.4e38f;
        #pragma unroll
        for (int t = 0; t < 7; ++t)
            #pragma unroll
            for (int r = 0; r < 4; ++r) {
                float v = acc[t][r] + bb;
                s += v; s2 += v*v;
                float va = sg * v;
                if (t*4 + r < 14) mx0 = fmaxf(mx0, va);
                else              mx1 = fmaxf(mx1, va);
            }
        osel[(size_t)(blockIdx.x*8 + 2*q    )*1024 + ocol] = (__bf16)(sg * mx0);
        osel[(size_t)(blockIdx.x*8 + 2*q + 1)*1024 + ocol] = (__bf16)(sg * mx1);
        s  += __shfl_xor(s, 16);  s  += __shfl_xor(s, 32);
        s2 += __shfl_xor(s2, 16); s2 += __shfl_xor(s2, 32);
        if (lane < 16) {
            pb[ocol]        = s;    // plain stores — summed by sreduce_kernel
            pb[1024 + ocol] = s2;
        }
    };

    #pragma unroll 1
    for (int cc = 0; cc < 16; cc += 2) {
        // even step: prefetch chunk cc+1 -> bB, compute cc from bA
        {
            const char* gb = gw + (size_t)(cc+1)*16384 + boffB;   // BYTES
            #pragma unroll
            for (int k4 = 0; k4 < 4; ++k4)
                bB[k4] = *reinterpret_cast<const bf16x8*>(gb + k4*4096);
        }
        step(cc, bA);
        // odd step: prefetch chunk cc+2 -> bA, compute cc+1 from bB
        if (cc + 2 < 16) {
            const char* gb = gw + (size_t)(cc+2)*16384 + boffB;   // BYTES
            #pragma unroll
            for (int k4 = 0; k4 < 4; ++k4)
                bA[k4] = *reinterpret_cast<const bf16x8*>(gb + k4*4096);
        }
        step(cc + 1, bB);
    }
}

// ---------------- sreduce: sum l5 partials -> flat slot4 ------------------
__global__ __launch_bounds__(256) void sreduce_kernel(
    const float* __restrict__ part, float* __restrict__ stats)
{
    const int cg  = blockIdx.x*256 + threadIdx.x;   // 0..4095
    const int inp = cg >> 11;
    const int col = cg & 2047;
    const float* p = part + (size_t)inp*512*2048 + col;
    float s = 0.f;
    #pragma unroll 4
    for (int b = 0; b < 512; ++b)
        s += p[(size_t)b*2048];
    stats[inp*INP_STRIDE + SLOT5_OFF + col] = s;
}

// ---------------- head+cluster, both inputs INTERLEAVED per block ----------
// One pass over k: both osel rows, shared embW loads; one 20-wide reduce;
// cluster distances share cluW loads. Barriers 6 -> 3, embW/cluW traffic
// halved, memory-level parallelism doubled.
__global__ __launch_bounds__(256) void headclu_kernel(
    const __bf16* __restrict__ osel,  // [2*NB][1024] bf16
    const float* __restrict__ stats,  // base
    const float* __restrict__ gamma, const float* __restrict__ beta,
    const float* __restrict__ embW, const float* __restrict__ embB,
    const float* __restrict__ cluW,
    float* __restrict__ e1, float* __restrict__ e2,
    float* __restrict__ c1, float* __restrict__ c2,
    float* __restrict__ d1, float* __restrict__ simOut)
{
    const int b = blockIdx.x, tid = threadIdx.x;
    const int wave = tid >> 6, lane = tid & 63;
    __shared__ float red[4][20];
    __shared__ float se[2][10];
    __shared__ float sred[4][2];

    const float* st0 = stats + SLOT5_OFF;
    const float* st1 = stats + INP_STRIDE + SLOT5_OFF;
    const __bf16* row0 = osel + (size_t)b*1024;
    const __bf16* row1 = osel + (size_t)(NB + b)*1024;

    float acc0[10], acc1[10];
    #pragma unroll
    for (int j = 0; j < 10; ++j) { acc0[j] = 0.f; acc1[j] = 0.f; }
    #pragma unroll
    for (int i = 0; i < 4; ++i) {
        int k = tid + i*256;
        float g = gamma[k], bt = beta[k];
        float mu0 = st0[k]*(1.f/NROWS);
        float va0 = st0[1024+k]*(1.f/NROWS) - mu0*mu0;
        float a0 = g*rsqrtf(va0+BN_EPS);
        float c0 = bt - mu0*a0;
        float mu1 = st1[k]*(1.f/NROWS);
        float va1 = st1[1024+k]*(1.f/NROWS) - mu1*mu1;
        float a1 = g*rsqrtf(va1+BN_EPS);
        float c1_ = bt - mu1*a1;
        float h0 = fmaxf(a0*(float)row0[k] + c0, 0.f);
        float h1 = fmaxf(a1*(float)row1[k] + c1_, 0.f);
        #pragma unroll
        for (int j = 0; j < 10; ++j) {
            float w = embW[k*10 + j];
            acc0[j] += h0 * w;
            acc1[j] += h1 * w;
        }
    }
    #pragma unroll
    for (int j = 0; j < 10; ++j) {
        acc0[j] += __shfl_down(acc0[j], 32);
        acc0[j] += __shfl_down(acc0[j], 16);
        acc0[j] += __shfl_down(acc0[j], 8);
        acc0[j] += __shfl_down(acc0[j], 4);
        acc0[j] += __shfl_down(acc0[j], 2);
        acc0[j] += __shfl_down(acc0[j], 1);
        acc1[j] += __shfl_down(acc1[j], 32);
        acc1[j] += __shfl_down(acc1[j], 16);
        acc1[j] += __shfl_down(acc1[j], 8);
        acc1[j] += __shfl_down(acc1[j], 4);
        acc1[j] += __shfl_down(acc1[j], 2);
        acc1[j] += __shfl_down(acc1[j], 1);
    }
    if (lane == 0)
        #pragma unroll
        for (int j = 0; j < 10; ++j) {
            red[wave][j]      = acc0[j];
            red[wave][10 + j] = acc1[j];
        }
    __syncthreads();
    if (tid < 20) {
        int inp = tid / 10, j = tid % 10;
        float t = red[0][tid]+red[1][tid]+red[2][tid]+red[3][tid] + embB[j];
        se[inp][j] = t;
        (inp ? e2 : e1)[b*10 + j] = t;
    }
    __syncthreads();

    float ev0[10], ev1[10];
    #pragma unroll
    for (int j = 0; j < 10; ++j) { ev0[j] = se[0][j]; ev1[j] = se[1][j]; }
    float d0loc[4], d1loc[4], q0loc[4], q1loc[4], qs0 = 0.f, qs1 = 0.f;
    #pragma unroll
    for (int i = 0; i < 4; ++i) {
        int mm = tid + i*256;
        float dd0 = 0.f, dd1 = 0.f;
        if (mm < 800) {
            #pragma unroll
            for (int j = 0; j < 10; ++j) {
                float cw = cluW[mm*10 + j];
                float t0 = ev0[j] - cw; dd0 += t0*t0;
                float t1 = ev1[j] - cw; dd1 += t1*t1;
            }
        }
        d0loc[i] = dd0; d1loc[i] = dd1;
        float q0v = (mm < 800) ? 1.f/(1.f + dd0) : 0.f;
        float q1v = (mm < 800) ? 1.f/(1.f + dd1) : 0.f;
        q0loc[i] = q0v; q1loc[i] = q1v;
        qs0 += q0v; qs1 += q1v;
    }
    float t0 = qs0, t1 = qs1;
    t0 += __shfl_down(t0,32); t0 += __shfl_down(t0,16); t0 += __shfl_down(t0,8);
    t0 += __shfl_down(t0,4);  t0 += __shfl_down(t0,2);  t0 += __shfl_down(t0,1);
    t1 += __shfl_down(t1,32); t1 += __shfl_down(t1,16); t1 += __shfl_down(t1,8);
    t1 += __shfl_down(t1,4);  t1 += __shfl_down(t1,2);  t1 += __shfl_down(t1,1);
    if (lane == 0) { sred[wave][0] = t0; sred[wave][1] = t1; }
    __syncthreads();
    float inv0 = 1.f / (sred[0][0]+sred[1][0]+sred[2][0]+sred[3][0]);
    float inv1 = 1.f / (sred[0][1]+sred[1][1]+sred[2][1]+sred[3][1]);
    #pragma unroll
    for (int i = 0; i < 4; ++i) {
        int mm = tid + i*256;
        if (mm < 800) {
            c1[(size_t)b*800 + mm] = q0loc[i]*inv0;
            c2[(size_t)b*800 + mm] = q1loc[i]*inv1;
            d1[(size_t)b*800 + mm] = d0loc[i];
        }
    }
    if (tid == 0) {
        float ss = 0.f;
        #pragma unroll
        for (int j = 0; j < 10; ++j) {
            float df = ev0[j] - ev1[j] + 1e-6f;
            ss += df*df;
        }
        simOut[b] = sqrtf(ss);
    }
}

// ---------------------------------------------------------------------------
extern "C" void kernel_launch(void* const* d_in, const int* in_sizes, int n_in,
                              void* d_out, int out_size, void* d_ws, size_t ws_size,
                              hipStream_t stream)
{
    const float* x1 = (const float*)d_in[0];
    const float* x2 = (const float*)d_in[1];
    const float *W[5], *bi[5], *ga[5], *be[5];
    for (int l = 0; l < 5; l++) {
        W[l]  = (const float*)d_in[2 + 4*l];
        bi[l] = (const float*)d_in[3 + 4*l];
        ga[l] = (const float*)d_in[4 + 4*l];
        be[l] = (const float*)d_in[5 + 4*l];
    }
    const float* embW = (const float*)d_in[22];
    const float* embB = (const float*)d_in[23];
    const float* cluW = (const float*)d_in[24];
    float* out = (float*)d_out;
    float* ws  = (float*)d_ws;

    // workspace (floats):
    //   stats 266240 (2 x 133120) | weights 73728 (bf16 x 147456)
    //   R1 = 8,388,608 : P0 bf16 [2*NROWS][64] / osel bf16 [2*NB][1024]
    //   R2 = 14,680,064: P1/Q bf16 [2*NROWS][128] (7.34M fl) + part 2.10M fl
    float*  stats = ws;
    __bf16* wt2   = (__bf16*)(ws + 2*INP_STRIDE);
    __bf16* wt3   = wt2 + 4096;
    __bf16* wt4   = wt2 + 8192;
    __bf16* wt5b  = wt2 + 16384;
    float*  R1f   = ws + 2*INP_STRIDE + 73728;
    float*  R2f   = R1f + 8388608;
    __bf16* P0    = (__bf16*)R1f;
    __bf16* P1    = (__bf16*)R2f;
    __bf16* Q     = (__bf16*)R2f;    // overwrites P1 (dead after layer 3)
    __bf16* osel  = (__bf16*)R1f;    // overwrites P0 (dead after layer 4)
    float*  part  = R2f + 7340032;   // after Q, no overlap

    // grid: zero 266240 + convert 147456 = 413696 items -> 1616 blocks
    wprep_kernel<<<1616, 256, 0, stream>>>(W[1], W[2], W[3], W[4],
                                           wt2, wt3, wt4, wt5b, stats);

    float* simO = out;
    float* c1O  = out + 4096;
    float* c2O  = out + 3280896;
    float* e1O  = out + 6557696;
    float* e2O  = out + 6598656;
    float* d1O  = out + 6639616;

    l1_kernel<<<2048, 256, 0, stream>>>(x1, x2, W[0], bi[0], P0, stats);
    layer_kernel<64><<<1024, 256, 0, stream>>>(
        P0, stats + 0*SLOT_STRIDE, ga[0], be[0], wt2, bi[1], P1, stats + 1*SLOT_STRIDE);
    layer_kernel<64><<<1024, 256, 0, stream>>>(
        P1, stats + 1*SLOT_STRIDE, ga[1], be[1], wt3, bi[2], P0, stats + 2*SLOT_STRIDE);
    layer_kernel<128><<<1024, 256, 0, stream>>>(
        P0, stats + 2*SLOT_STRIDE, ga[2], be[2], wt4, bi[3], Q, stats + 3*SLOT_STRIDE);
    l5_kernel<<<1024, 256, 0, stream>>>(
        Q, stats + 3*SLOT_STRIDE, ga[3], be[3], wt5b, bi[4], ga[4], osel, part);
    sreduce_kernel<<<16, 256, 0, stream>>>(part, stats);
    headclu_kernel<<<4096, 256, 0, stream>>>(
        osel, stats, ga[4], be[4], embW, embB, cluW,
        e1O, e2O, c1O, c2O, d1O, simO);
}

// Round 20
// 249.913 us; speedup vs baseline: 1.4834x; 1.1525x over previous
//
#include <hip/hip_runtime.h>
#include <hip/hip_bf16.h>

#define NB 4096
#define PLEN 14
#define NROWS (NB*PLEN)     // 57344 per input
#define BN_EPS 1e-5f

// stats layout (floats): input i at +i*133120.
//   slot L (L=0..3, banked): +L*32768, 16 banks x {1024 sums, 1024 sumsq}
//   slot 4 (flat, from sreduce): +131072, {1024 sums, 1024 sumsq}
#define SLOT_STRIDE 32768
#define INP_STRIDE  133120
#define SLOT5_OFF   131072
#define NBANK 16

typedef __bf16 bf16x8 __attribute__((ext_vector_type(8)));
typedef float  f32x4  __attribute__((ext_vector_type(4)));

// ---------------- wprep: zero stats + all weight converts in one launch ----
__global__ __launch_bounds__(256) void wprep_kernel(
    const float* __restrict__ W2, const float* __restrict__ W3,
    const float* __restrict__ W4, const float* __restrict__ W5,
    __bf16* __restrict__ wt2, __bf16* __restrict__ wt3,
    __bf16* __restrict__ wt4, __bf16* __restrict__ wt5b,
    float* __restrict__ stats)
{
    int idx = blockIdx.x*256 + threadIdx.x;
    if (idx < 2*INP_STRIDE) { stats[idx] = 0.f; return; }
    idx -= 2*INP_STRIDE;
    if (idx < 4096) { int n = idx>>6, k = idx&63; wt2[idx] = (__bf16)W2[k*64+n]; return; }
    idx -= 4096;
    if (idx < 4096) { int n = idx>>6, k = idx&63; wt3[idx] = (__bf16)W3[k*64+n]; return; }
    idx -= 4096;
    if (idx < 8192) { int n = idx>>6, k = idx&63; wt4[idx] = (__bf16)W4[k*128+n]; return; }
    idx -= 8192;
    // W5 blocked: [16 c][16 kg][64 n][8 kk]
    int kk = idx & 7, n = (idx >> 3) & 63, kg = (idx >> 9) & 15, c = idx >> 13;
    wt5b[idx] = (__bf16)W5[(kg*8 + kk)*1024 + c*64 + n];
}

// ---------------- Layer 1 (both inputs): agg(x) @ W1 + b1, stats ----------
// Stats via BANKED atomics (bank = blockIdx&15): chain depth 1024 -> 64.
__global__ __launch_bounds__(256) void l1_kernel(
    const float* __restrict__ x1,    // [NB][3][PLEN]
    const float* __restrict__ x2,
    const float* __restrict__ W,     // [3][64]
    const float* __restrict__ bias,  // [64]
    __bf16* __restrict__ pre,        // [2*NROWS][64] bf16
    float* __restrict__ stats)       // base (slot0 banked)
{
    const int col  = threadIdx.x & 63;
    const int sub  = threadIdx.x >> 6;
    const int chain = blockIdx.x * 4 + sub;      // 0..8191 global
    const int inp  = chain >> 12;                // uniform per block
    const int bank = blockIdx.x & (NBANK-1);
    const float w0 = W[0*64+col], w1 = W[1*64+col], w2 = W[2*64+col];
    const float bb = bias[col];
    const float* xb = (inp ? x2 : x1) + (chain & 4095)*3*PLEN;
    float s = 0.f, s2 = 0.f;
    for (int p = 0; p < PLEN; p++) {
        float u0 = 0.f, u1 = 0.f, u2 = 0.f;
        if (p > 0)      { u0 += xb[p-1]; u1 += xb[PLEN+p-1]; u2 += xb[2*PLEN+p-1]; }
        if (p < PLEN-1) { u0 += xb[p+1]; u1 += xb[PLEN+p+1]; u2 += xb[2*PLEN+p+1]; }
        float v = u0*w0 + u1*w1 + u2*w2 + bb;
        pre[(size_t)(chain*PLEN + p)*64 + col] = (__bf16)v;
        s += v; s2 += v*v;
    }
    __shared__ float ss[4][64], ssq[4][64];
    ss[sub][col] = s; ssq[sub][col] = s2;
    __syncthreads();
    if (sub == 0) {
        float ts  = ss[0][col]+ss[1][col]+ss[2][col]+ss[3][col];
        float ts2 = ssq[0][col]+ssq[1][col]+ssq[2][col]+ssq[3][col];
        float* st = stats + inp*INP_STRIDE + bank*2048;
        atomicAdd(&st[col], ts);
        atomicAdd(&st[1024 + col], ts2);
    }
}

// ---------------- fused layer (2-4), both inputs: BN+ReLU+agg -> GEMM -----
// M-TILE 56 (4 chains), grid 2048 (was 112/1024): halves the per-block
// critical path {stats prologue -> row loads -> barrier -> MFMA -> epilogue}
// and doubles TLP. sA padded to 64 rows for 4 MFMA t-tiles; pad rows zeroed
// and excluded from stores/stats via the (t==3 && q>=2) guard.
template<int NOUT>
__global__ __launch_bounds__(256) void layer_kernel(
    const __bf16* __restrict__ prev,     // [2*NROWS][64] bf16
    const float* __restrict__ stats_in,  // input-0 slot base (banked)
    const float* __restrict__ gamma, const float* __restrict__ beta,
    const __bf16* __restrict__ wt,       // [NOUT][64]
    const float* __restrict__ bias,      // [NOUT]
    __bf16* __restrict__ outp,           // [2*NROWS][NOUT] bf16
    float* __restrict__ stats_out)       // input-0 slot base (banked)
{
    constexpr int KP = 72;
    constexpr int NCH = NOUT/64;
    __shared__ __align__(16) short sA[64*KP];        // 9216 B
    const int tid = threadIdx.x, wave = tid >> 6, lane = tid & 63;
    const int m = lane & 15, q = lane >> 4;
    const int rowbase = blockIdx.x * 56;             // global over 114688 rows
    const int soff = (blockIdx.x >> 10) * INP_STRIDE;// 1024 blocks/input
    const int bank = blockIdx.x & (NBANK-1);
    const float* sin_ = stats_in + soff;

    // B -> registers (L2-hot, 8/16 KB total)
    bf16x8 breg[NCH][2];
    #pragma unroll
    for (int cc = 0; cc < NCH; ++cc)
        #pragma unroll
        for (int ksi = 0; ksi < 2; ++ksi)
            breg[cc][ksi] = *reinterpret_cast<const bf16x8*>(
                wt + (cc*64 + wave*16 + m)*64 + ksi*32 + q*8);

    // zero pad rows 56..63 (cols 0..63)
    #pragma unroll
    for (int i = tid; i < 512; i += 256) {
        int rr = 56 + (i >> 6), cc = i & 63;
        sA[rr*KP + cc] = 0;
    }
    // build A = chain_agg(relu(bn(prev))): thread owns 1 chain x 1 col
    {
        const int ch = tid >> 6, c = tid & 63;       // 4 chains
        float sb = 0.f, qb = 0.f;
        #pragma unroll
        for (int bk = 0; bk < NBANK; ++bk) {
            sb += sin_[bk*2048 + c];
            qb += sin_[bk*2048 + 1024 + c];
        }
        float mu = sb*(1.f/NROWS);
        float vr = qb*(1.f/NROWS) - mu*mu;
        float a = gamma[c]*rsqrtf(vr+BN_EPS), c0 = beta[c]-mu*a;
        float h[14];
        const __bf16* src = prev + (size_t)(rowbase + ch*14)*64 + c;
        #pragma unroll
        for (int r = 0; r < 14; ++r)
            h[r] = fmaxf(a*(float)src[r*64] + c0, 0.f);
        #pragma unroll
        for (int r = 0; r < 14; ++r) {
            float g = (r>0 ? h[r-1] : 0.f) + (r<13 ? h[r+1] : 0.f);
            union { __bf16 b; short s; } pk;
            pk.b = (__bf16)g;
            sA[(ch*14+r)*KP + c] = pk.s;
        }
    }
    __syncthreads();

    f32x4 acc[NCH][4];
    #pragma unroll
    for (int cc = 0; cc < NCH; ++cc)
        #pragma unroll
        for (int t = 0; t < 4; ++t) acc[cc][t] = (f32x4){0.f,0.f,0.f,0.f};

    #pragma unroll
    for (int ksi = 0; ksi < 2; ++ksi) {
        bf16x8 af[4];
        #pragma unroll
        for (int t = 0; t < 4; ++t)
            af[t] = *reinterpret_cast<const bf16x8*>(&sA[(t*16+m)*KP + ksi*32 + q*8]);
        #pragma unroll
        for (int cc = 0; cc < NCH; ++cc)
            #pragma unroll
            for (int t = 0; t < 4; ++t)
                acc[cc][t] = __builtin_amdgcn_mfma_f32_16x16x32_bf16(af[t], breg[cc][ksi], acc[cc][t], 0, 0, 0);
    }

    float* stout = stats_out + soff + bank*2048;
    #pragma unroll
    for (int cc = 0; cc < NCH; ++cc) {
        const int ocol = cc*64 + wave*16 + m;
        const float bb = bias[ocol];
        float s = 0.f, s2 = 0.f;
        #pragma unroll
        for (int t = 0; t < 4; ++t) {
            if (t == 3 && q >= 2) continue;          // rows 56..63 are pad
            #pragma unroll
            for (int r = 0; r < 4; ++r) {
                float v = acc[cc][t][r] + bb;
                outp[(size_t)(rowbase + t*16 + q*4 + r)*NOUT + ocol] = (__bf16)v;
                s += v; s2 += v*v;
            }
        }
        s  += __shfl_xor(s, 16);  s  += __shfl_xor(s, 32);
        s2 += __shfl_xor(s2, 16); s2 += __shfl_xor(s2, 32);
        if (lane < 16) {
            atomicAdd(&stout[ocol], s);
            atomicAdd(&stout[1024 + ocol], s2);
        }
    }
}

// ---------------- Layer 5 (both inputs), 256 threads / 4 waves -------------
// Barrier-free main loop, B streamed through registers, bf16 in/out.
// BANKED stats in (slot3); partial-store stats out (validated round 16).
__global__ __launch_bounds__(256, 1) void l5_kernel(
    const __bf16* __restrict__ prev,     // [2*NROWS][128] bf16 (pre4)
    const float* __restrict__ stats_in,  // input-0 slot3 base (banked)
    const float* __restrict__ gamma, const float* __restrict__ beta,
    const __bf16* __restrict__ wtb,      // blocked W5: [16 c][16 kg][64 n][8 kk]
    const float* __restrict__ bias,      // [1024]
    const float* __restrict__ g5,        // gamma5 [1024] (sign select)
    __bf16* __restrict__ osel,           // [2*NB][1024] bf16
    float* __restrict__ part)            // [1024 blocks][2048] partial stats
{
    __shared__ __align__(16) short sA[112*136];   // 30464 B, permuted A rows
    const int tid = threadIdx.x, wave = tid >> 6, lane = tid & 63;
    const int m = lane & 15, q = lane >> 4;
    const int rowbase = blockIdx.x * 112;
    const int soff = (blockIdx.x >> 9) * INP_STRIDE;
    const float* sin_ = stats_in + soff;
    float* pb = part + (size_t)blockIdx.x * 2048;

    // per-lane B offset within a 16KB chunk, in BYTES: kg = k4*4+q (stride
    // 1024 B), n = wave*16+m (stride 16 B); k4 stride = 4 kg = 4096 B.
    const char* gw = (const char*)wtb;
    const int boffB = q*1024 + (wave*16 + m)*16;

    // prefetch B chunk 0 into registers (covered by A staging below)
    bf16x8 bA[4], bB[4];
    #pragma unroll
    for (int k4 = 0; k4 < 4; ++k4)
        bA[k4] = *reinterpret_cast<const bf16x8*>(gw + boffB + k4*4096);

    // build A = chain_agg(relu(bn(pre4))), PERMUTED rows: thread owns 1 chain x 4 cols
    {
        const int ch = tid >> 5, c4 = (tid & 31)*4;
        float aa[4], cc4[4];
        #pragma unroll
        for (int j = 0; j < 4; ++j) {
            float sb = 0.f, qb = 0.f;
            #pragma unroll
            for (int bk = 0; bk < NBANK; ++bk) {
                sb += sin_[bk*2048 + c4+j];
                qb += sin_[bk*2048 + 1024 + c4+j];
            }
            float mu = sb*(1.f/NROWS);
            float vr = qb*(1.f/NROWS) - mu*mu;
            aa[j] = gamma[c4+j]*rsqrtf(vr+BN_EPS);
            cc4[j] = beta[c4+j] - mu*aa[j];
        }
        float h[14][4];
        const __bf16* src = prev + (size_t)(rowbase + ch*14)*128 + c4;
        #pragma unroll
        for (int r = 0; r < 14; ++r) {
            union { uint2 u; __bf16 b[4]; } ld;
            ld.u = *reinterpret_cast<const uint2*>(src + r*128);
            h[r][0] = fmaxf(aa[0]*(float)ld.b[0] + cc4[0], 0.f);
            h[r][1] = fmaxf(aa[1]*(float)ld.b[1] + cc4[1], 0.f);
            h[r][2] = fmaxf(aa[2]*(float)ld.b[2] + cc4[2], 0.f);
            h[r][3] = fmaxf(aa[3]*(float)ld.b[3] + cc4[3], 0.f);
        }
        const int qq = ch >> 1, jb = (ch & 1) * 14;
        #pragma unroll
        for (int p = 0; p < 14; ++p) {
            int j = jb + p;
            int slot = (j>>2)*16 + qq*4 + (j&3);
            union { __bf16 b[4]; uint2 u; } pk;
            #pragma unroll
            for (int jj = 0; jj < 4; ++jj) {
                float g = (p>0 ? h[p-1][jj] : 0.f) + (p<13 ? h[p+1][jj] : 0.f);
                pk.b[jj] = (__bf16)g;
            }
            *reinterpret_cast<uint2*>(&sA[slot*136 + c4]) = pk.u;
        }
    }
    __syncthreads();   // the ONLY barrier: sA complete

    // A fragments -> registers (sA never touched again)
    bf16x8 af[7][4];
    #pragma unroll
    for (int t = 0; t < 7; ++t)
        #pragma unroll
        for (int kk = 0; kk < 4; ++kk)
            af[t][kk] = *reinterpret_cast<const bf16x8*>(&sA[(t*16 + m)*136 + kk*32 + q*8]);

    // one c-step: MFMA from bR, epilogue (register chain-max + partial store)
    auto step = [&](int c, bf16x8 (&bR)[4]) {
        f32x4 acc[7];
        #pragma unroll
        for (int t = 0; t < 7; ++t) acc[t] = (f32x4){0.f,0.f,0.f,0.f};
        #pragma unroll
        for (int k4 = 0; k4 < 4; ++k4)
            #pragma unroll
            for (int t = 0; t < 7; ++t)
                acc[t] = __builtin_amdgcn_mfma_f32_16x16x32_bf16(af[t][k4], bR[k4], acc[t], 0, 0, 0);
        const int ocol = c*64 + wave*16 + m;
        const float bb = bias[ocol];
        const float sg = (g5[ocol] >= 0.f) ? 1.f : -1.f;
        float s = 0.f, s2 = 0.f;
        float mx0 = -3.4e38f, mx1 = -3.4e38f;
        #pragma unroll
        for (int t = 0; t < 7; ++t)
            #pragma unroll
            for (int r = 0; r < 4; ++r) {
                float v = acc[t][r] + bb;
                s += v; s2 += v*v;
                float va = sg * v;
                if (t*4 + r < 14) mx0 = fmaxf(mx0, va);
                else              mx1 = fmaxf(mx1, va);
            }
        osel[(size_t)(blockIdx.x*8 + 2*q    )*1024 + ocol] = (__bf16)(sg * mx0);
        osel[(size_t)(blockIdx.x*8 + 2*q + 1)*1024 + ocol] = (__bf16)(sg * mx1);
        s  += __shfl_xor(s, 16);  s  += __shfl_xor(s, 32);
        s2 += __shfl_xor(s2, 16); s2 += __shfl_xor(s2, 32);
        if (lane < 16) {
            pb[ocol]        = s;    // plain stores — summed by sreduce_kernel
            pb[1024 + ocol] = s2;
        }
    };

    #pragma unroll 1
    for (int cc = 0; cc < 16; cc += 2) {
        // even step: prefetch chunk cc+1 -> bB, compute cc from bA
        {
            const char* gb = gw + (size_t)(cc+1)*16384 + boffB;   // BYTES
            #pragma unroll
            for (int k4 = 0; k4 < 4; ++k4)
                bB[k4] = *reinterpret_cast<const bf16x8*>(gb + k4*4096);
        }
        step(cc, bA);
        // odd step: prefetch chunk cc+2 -> bA, compute cc+1 from bB
        if (cc + 2 < 16) {
            const char* gb = gw + (size_t)(cc+2)*16384 + boffB;   // BYTES
            #pragma unroll
            for (int k4 = 0; k4 < 4; ++k4)
                bA[k4] = *reinterpret_cast<const bf16x8*>(gb + k4*4096);
        }
        step(cc + 1, bB);
    }
}

// ---------------- sreduce v2: 256 blocks, 32 partials/thread + atomicAdd ---
// 16 slices of 32 blocks per (inp,col); depth-16 atomic chains into the
// wprep-zeroed flat slot4. Replaces the 16-block near-idle version (~10us).
__global__ __launch_bounds__(256) void sreduce_kernel(
    const float* __restrict__ part, float* __restrict__ stats)
{
    const int g = blockIdx.x*256 + threadIdx.x;     // 0..65535
    const int slice = g >> 12;                      // 0..15
    const int pair  = g & 4095;
    const int inp = pair >> 11;
    const int col = pair & 2047;
    const float* p = part + (size_t)inp*512*2048 + (size_t)slice*32*2048 + col;
    float s = 0.f;
    #pragma unroll 4
    for (int b = 0; b < 32; ++b)
        s += p[(size_t)b*2048];
    atomicAdd(&stats[inp*INP_STRIDE + SLOT5_OFF + col], s);
}

// ---------------- head+cluster, both inputs INTERLEAVED per block ----------
__global__ __launch_bounds__(256) void headclu_kernel(
    const __bf16* __restrict__ osel,  // [2*NB][1024] bf16
    const float* __restrict__ stats,  // base
    const float* __restrict__ gamma, const float* __restrict__ beta,
    const float* __restrict__ embW, const float* __restrict__ embB,
    const float* __restrict__ cluW,
    float* __restrict__ e1, float* __restrict__ e2,
    float* __restrict__ c1, float* __restrict__ c2,
    float* __restrict__ d1, float* __restrict__ simOut)
{
    const int b = blockIdx.x, tid = threadIdx.x;
    const int wave = tid >> 6, lane = tid & 63;
    __shared__ float red[4][20];
    __shared__ float se[2][10];
    __shared__ float sred[4][2];

    const float* st0 = stats + SLOT5_OFF;
    const float* st1 = stats + INP_STRIDE + SLOT5_OFF;
    const __bf16* row0 = osel + (size_t)b*1024;
    const __bf16* row1 = osel + (size_t)(NB + b)*1024;

    float acc0[10], acc1[10];
    #pragma unroll
    for (int j = 0; j < 10; ++j) { acc0[j] = 0.f; acc1[j] = 0.f; }
    #pragma unroll
    for (int i = 0; i < 4; ++i) {
        int k = tid + i*256;
        float g = gamma[k], bt = beta[k];
        float mu0 = st0[k]*(1.f/NROWS);
        float va0 = st0[1024+k]*(1.f/NROWS) - mu0*mu0;
        float a0 = g*rsqrtf(va0+BN_EPS);
        float c0 = bt - mu0*a0;
        float mu1 = st1[k]*(1.f/NROWS);
        float va1 = st1[1024+k]*(1.f/NROWS) - mu1*mu1;
        float a1 = g*rsqrtf(va1+BN_EPS);
        float c1_ = bt - mu1*a1;
        float h0 = fmaxf(a0*(float)row0[k] + c0, 0.f);
        float h1 = fmaxf(a1*(float)row1[k] + c1_, 0.f);
        #pragma unroll
        for (int j = 0; j < 10; ++j) {
            float w = embW[k*10 + j];
            acc0[j] += h0 * w;
            acc1[j] += h1 * w;
        }
    }
    #pragma unroll
    for (int j = 0; j < 10; ++j) {
        acc0[j] += __shfl_down(acc0[j], 32);
        acc0[j] += __shfl_down(acc0[j], 16);
        acc0[j] += __shfl_down(acc0[j], 8);
        acc0[j] += __shfl_down(acc0[j], 4);
        acc0[j] += __shfl_down(acc0[j], 2);
        acc0[j] += __shfl_down(acc0[j], 1);
        acc1[j] += __shfl_down(acc1[j], 32);
        acc1[j] += __shfl_down(acc1[j], 16);
        acc1[j] += __shfl_down(acc1[j], 8);
        acc1[j] += __shfl_down(acc1[j], 4);
        acc1[j] += __shfl_down(acc1[j], 2);
        acc1[j] += __shfl_down(acc1[j], 1);
    }
    if (lane == 0)
        #pragma unroll
        for (int j = 0; j < 10; ++j) {
            red[wave][j]      = acc0[j];
            red[wave][10 + j] = acc1[j];
        }
    __syncthreads();
    if (tid < 20) {
        int inp = tid / 10, j = tid % 10;
        float t = red[0][tid]+red[1][tid]+red[2][tid]+red[3][tid] + embB[j];
        se[inp][j] = t;
        (inp ? e2 : e1)[b*10 + j] = t;
    }
    __syncthreads();

    float ev0[10], ev1[10];
    #pragma unroll
    for (int j = 0; j < 10; ++j) { ev0[j] = se[0][j]; ev1[j] = se[1][j]; }
    float d0loc[4], d1loc[4], q0loc[4], q1loc[4], qs0 = 0.f, qs1 = 0.f;
    #pragma unroll
    for (int i = 0; i < 4; ++i) {
        int mm = tid + i*256;
        float dd0 = 0.f, dd1 = 0.f;
        if (mm < 800) {
            #pragma unroll
            for (int j = 0; j < 10; ++j) {
                float cw = cluW[mm*10 + j];
                float t0 = ev0[j] - cw; dd0 += t0*t0;
                float t1 = ev1[j] - cw; dd1 += t1*t1;
            }
        }
        d0loc[i] = dd0; d1loc[i] = dd1;
        float q0v = (mm < 800) ? 1.f/(1.f + dd0) : 0.f;
        float q1v = (mm < 800) ? 1.f/(1.f + dd1) : 0.f;
        q0loc[i] = q0v; q1loc[i] = q1v;
        qs0 += q0v; qs1 += q1v;
    }
    float t0 = qs0, t1 = qs1;
    t0 += __shfl_down(t0,32); t0 += __shfl_down(t0,16); t0 += __shfl_down(t0,8);
    t0 += __shfl_down(t0,4);  t0 += __shfl_down(t0,2);  t0 += __shfl_down(t0,1);
    t1 += __shfl_down(t1,32); t1 += __shfl_down(t1,16); t1 += __shfl_down(t1,8);
    t1 += __shfl_down(t1,4);  t1 += __shfl_down(t1,2);  t1 += __shfl_down(t1,1);
    if (lane == 0) { sred[wave][0] = t0; sred[wave][1] = t1; }
    __syncthreads();
    float inv0 = 1.f / (sred[0][0]+sred[1][0]+sred[2][0]+sred[3][0]);
    float inv1 = 1.f / (sred[0][1]+sred[1][1]+sred[2][1]+sred[3][1]);
    #pragma unroll
    for (int i = 0; i < 4; ++i) {
        int mm = tid + i*256;
        if (mm < 800) {
            c1[(size_t)b*800 + mm] = q0loc[i]*inv0;
            c2[(size_t)b*800 + mm] = q1loc[i]*inv1;
            d1[(size_t)b*800 + mm] = d0loc[i];
        }
    }
    if (tid == 0) {
        float ss = 0.f;
        #pragma unroll
        for (int j = 0; j < 10; ++j) {
            float df = ev0[j] - ev1[j] + 1e-6f;
            ss += df*df;
        }
        simOut[b] = sqrtf(ss);
    }
}

// ---------------------------------------------------------------------------
extern "C" void kernel_launch(void* const* d_in, const int* in_sizes, int n_in,
                              void* d_out, int out_size, void* d_ws, size_t ws_size,
                              hipStream_t stream)
{
    const float* x1 = (const float*)d_in[0];
    const float* x2 = (const float*)d_in[1];
    const float *W[5], *bi[5], *ga[5], *be[5];
    for (int l = 0; l < 5; l++) {
        W[l]  = (const float*)d_in[2 + 4*l];
        bi[l] = (const float*)d_in[3 + 4*l];
        ga[l] = (const float*)d_in[4 + 4*l];
        be[l] = (const float*)d_in[5 + 4*l];
    }
    const float* embW = (const float*)d_in[22];
    const float* embB = (const float*)d_in[23];
    const float* cluW = (const float*)d_in[24];
    float* out = (float*)d_out;
    float* ws  = (float*)d_ws;

    // workspace (floats):
    //   stats 266240 (2 x 133120) | weights 73728 (bf16 x 147456)
    //   R1 = 8,388,608 : P0 bf16 [2*NROWS][64] / osel bf16 [2*NB][1024]
    //   R2 = 14,680,064: P1/Q bf16 [2*NROWS][128] (7.34M fl) + part 2.10M fl
    float*  stats = ws;
    __bf16* wt2   = (__bf16*)(ws + 2*INP_STRIDE);
    __bf16* wt3   = wt2 + 4096;
    __bf16* wt4   = wt2 + 8192;
    __bf16* wt5b  = wt2 + 16384;
    float*  R1f   = ws + 2*INP_STRIDE + 73728;
    float*  R2f   = R1f + 8388608;
    __bf16* P0    = (__bf16*)R1f;
    __bf16* P1    = (__bf16*)R2f;
    __bf16* Q     = (__bf16*)R2f;    // overwrites P1 (dead after layer 3)
    __bf16* osel  = (__bf16*)R1f;    // overwrites P0 (dead after layer 4)
    float*  part  = R2f + 7340032;   // after Q, no overlap

    // grid: zero 266240 + convert 147456 = 413696 items -> 1616 blocks
    wprep_kernel<<<1616, 256, 0, stream>>>(W[1], W[2], W[3], W[4],
                                           wt2, wt3, wt4, wt5b, stats);

    float* simO = out;
    float* c1O  = out + 4096;
    float* c2O  = out + 3280896;
    float* e1O  = out + 6557696;
    float* e2O  = out + 6598656;
    float* d1O  = out + 6639616;

    l1_kernel<<<2048, 256, 0, stream>>>(x1, x2, W[0], bi[0], P0, stats);
    layer_kernel<64><<<2048, 256, 0, stream>>>(
        P0, stats + 0*SLOT_STRIDE, ga[0], be[0], wt2, bi[1], P1, stats + 1*SLOT_STRIDE);
    layer_kernel<64><<<2048, 256, 0, stream>>>(
        P1, stats + 1*SLOT_STRIDE, ga[1], be[1], wt3, bi[2], P0, stats + 2*SLOT_STRIDE);
    layer_kernel<128><<<2048, 256, 0, stream>>>(
        P0, stats + 2*SLOT_STRIDE, ga[2], be[2], wt4, bi[3], Q, stats + 3*SLOT_STRIDE);
    l5_kernel<<<1024, 256, 0, stream>>>(
        Q, stats + 3*SLOT_STRIDE, ga[3], be[3], wt5b, bi[4], ga[4], osel, part);
    sreduce_kernel<<<256, 256, 0, stream>>>(part, stats);
    headclu_kernel<<<4096, 256, 0, stream>>>(
        osel, stats, ga[4], be[4], embW, embB, cluW,
        e1O, e2O, c1O, c2O, d1O, simO);
}